// Round 11
// baseline (1304.079 us; speedup 1.0000x reference)
//
#include <hip/hip_runtime.h>

#define NN 50000
#define NE 600000
#define DIM 128
#define NLAYERS 8
#define NCLASSES 10
#define NGRAPHS 64
#define BN_EPS 1e-5f
#define SLOPE 0.01f

typedef __attribute__((ext_vector_type(8))) short bf16x8;
typedef __attribute__((ext_vector_type(4))) float f32x4;

__device__ __forceinline__ float lrelu(float v) { return v > 0.f ? v : SLOPE * v; }

__device__ __forceinline__ unsigned short f2bf(float x) {
    unsigned u = __builtin_bit_cast(unsigned, x);
    unsigned r = (u + 0x7FFFu + ((u >> 16) & 1u)) >> 16;
    return (unsigned short)r;
}
__device__ __forceinline__ float bf2f(unsigned short h) {
    return __builtin_bit_cast(float, (unsigned)h << 16);
}
// split x into hi+lo bf16 pair: hi = bf16(x), lo = bf16(x - hi)
__device__ __forceinline__ void split8(const float* __restrict__ p, bf16x8& hi, bf16x8& lo) {
#pragma unroll
    for (int j = 0; j < 8; j++) {
        float x = p[j];
        unsigned short h = f2bf(x);
        hi[j] = (short)h;
        lo[j] = (short)f2bf(x - bf2f(h));
    }
}

// ---------------- CSR build: degree histogram
__global__ __launch_bounds__(256) void degree_kernel(const int* __restrict__ edges,
                                                     int* __restrict__ counts) {
    int e = blockIdx.x * 256 + threadIdx.x;
    if (e >= NE) return;
    atomicAdd(&counts[edges[NE + e]], 1);
}

// ---------------- CSR build: exclusive scan of counts -> offsets (single block)
__global__ __launch_bounds__(1024) void scan_kernel(const int* __restrict__ counts,
                                                    int* __restrict__ offsets) {
    __shared__ int wsum[16];
    __shared__ int carry;
    int lane = threadIdx.x & 63, wid = threadIdx.x >> 6;
    if (threadIdx.x == 0) { carry = 0; offsets[0] = 0; }
    __syncthreads();
    for (int base = 0; base < NN; base += 1024) {
        int i = base + threadIdx.x;
        int v = (i < NN) ? counts[i] : 0;
        int s = v;
#pragma unroll
        for (int o = 1; o < 64; o <<= 1) {
            int t = __shfl_up(s, o);
            if (lane >= o) s += t;
        }
        if (lane == 63) wsum[wid] = s;
        __syncthreads();
        if (wid == 0 && lane < 16) {
            int w = wsum[lane];
            int sw = w;
#pragma unroll
            for (int o = 1; o < 16; o <<= 1) {
                int t = __shfl_up(sw, o);
                if (lane >= o) sw += t;
            }
            wsum[lane] = sw - w;  // exclusive
        }
        __syncthreads();
        int incl = s + wsum[wid] + carry;
        if (i < NN) offsets[i + 1] = incl;
        __syncthreads();
        if (threadIdx.x == 1023) carry = incl;
        __syncthreads();
    }
}

// ---------------- CSR build: fill src lists
__global__ __launch_bounds__(256) void fill_kernel(const int* __restrict__ edges,
                                                   int* __restrict__ cursor,
                                                   int* __restrict__ csr_src) {
    int e = blockIdx.x * 256 + threadIdx.x;
    if (e >= NE) return;
    int d = edges[NE + e];
    int p = atomicAdd(&cursor[d], 1);
    csr_src[p] = edges[e];
}

// ---------------- weight prep: hi/lo bf16 of W^T.  Wt[mat][n][k] = bf16(W[k][n])
__global__ __launch_bounds__(256) void wprep_kernel(const float* __restrict__ W1s,
                                                    const float* __restrict__ W2s,
                                                    unsigned short* __restrict__ Wh,
                                                    unsigned short* __restrict__ Wl) {
    int gid = blockIdx.x * 256 + threadIdx.x;  // 16 * 16384
    if (gid >= 16 * 16384) return;
    int mat = gid >> 14;
    int idx = gid & 16383;
    int n = idx >> 7, k = idx & 127;
    int layer = mat >> 1, which = mat & 1;
    const float* src = which ? (W2s + (size_t)layer * 16384) : (W1s + (size_t)layer * 16384);
    float x = src[k * DIM + n];
    unsigned short h = f2bf(x);
    Wh[gid] = h;
    Wl[gid] = f2bf(x - bf2f(h));
}

// ---------------- gather (+ inline BN finalize + lrelu of producing layer):
// hz[i] = f(z[i]) + sum_{j in N(i)} f(z[j]);  f = BN ? lrelu(z*sc+sh) : z
// ILP form: lane-parallel index fetch + 4-deep row-load unroll.
template <int BN>
__global__ __launch_bounds__(256) void gather_kernel(const float* __restrict__ Zin,
                                                     const float* __restrict__ stats,
                                                     const float* __restrict__ gamma,
                                                     const float* __restrict__ beta,
                                                     const int* __restrict__ offsets,
                                                     const int* __restrict__ csr_src,
                                                     float* __restrict__ hz) {
    int node = blockIdx.x * 4 + (threadIdx.x >> 6);
    if (node >= NN) return;
    int lane = threadIdx.x & 63;
    size_t coloff = (size_t)lane * 2;
    float scx = 0.f, scy = 0.f, shx = 0.f, shy = 0.f;
    if (BN) {
        int c0 = lane * 2, c1 = lane * 2 + 1;
        float mu0 = stats[c0] * (1.f / NN);
        float mu1 = stats[c1] * (1.f / NN);
        float var0 = stats[DIM + c0] * (1.f / NN) - mu0 * mu0;
        float var1 = stats[DIM + c1] * (1.f / NN) - mu1 * mu1;
        scx = gamma[c0] * rsqrtf(var0 + BN_EPS);
        scy = gamma[c1] * rsqrtf(var1 + BN_EPS);
        shx = beta[c0] - mu0 * scx;
        shy = beta[c1] - mu1 * scy;
    }
    int beg = offsets[node], end = offsets[node + 1];
    float2 v = *(const float2*)(Zin + (size_t)node * DIM + coloff);
    float ax, ay;
    if (BN) { ax = lrelu(v.x * scx + shx); ay = lrelu(v.y * scy + shy); }
    else    { ax = v.x; ay = v.y; }

    for (int base = beg; base < end; base += 64) {
        int cnt = min(64, end - base);
        int myidx = (lane < cnt) ? csr_src[base + lane] : 0;
        int e = 0;
        for (; e + 4 <= cnt; e += 4) {
            int i0 = __shfl(myidx, e);
            int i1 = __shfl(myidx, e + 1);
            int i2 = __shfl(myidx, e + 2);
            int i3 = __shfl(myidx, e + 3);
            float2 w0 = *(const float2*)(Zin + (size_t)i0 * DIM + coloff);
            float2 w1 = *(const float2*)(Zin + (size_t)i1 * DIM + coloff);
            float2 w2 = *(const float2*)(Zin + (size_t)i2 * DIM + coloff);
            float2 w3 = *(const float2*)(Zin + (size_t)i3 * DIM + coloff);
            if (BN) {
                ax += lrelu(w0.x * scx + shx) + lrelu(w1.x * scx + shx) +
                      lrelu(w2.x * scx + shx) + lrelu(w3.x * scx + shx);
                ay += lrelu(w0.y * scy + shy) + lrelu(w1.y * scy + shy) +
                      lrelu(w2.y * scy + shy) + lrelu(w3.y * scy + shy);
            } else {
                ax += (w0.x + w1.x) + (w2.x + w3.x);
                ay += (w0.y + w1.y) + (w2.y + w3.y);
            }
        }
        for (; e < cnt; e++) {
            int i0 = __shfl(myidx, e);
            float2 w = *(const float2*)(Zin + (size_t)i0 * DIM + coloff);
            if (BN) { ax += lrelu(w.x * scx + shx); ay += lrelu(w.y * scy + shy); }
            else    { ax += w.x; ay += w.y; }
        }
    }
    float2 o; o.x = ax; o.y = ay;
    *(float2*)(hz + (size_t)node * DIM + coloff) = o;
}

// ---------------- fused MLP on matrix cores, split-bf16 (3-product) precision.
// ILP v2: 3 independent MFMA accumulator chains per nt; register double-buffered
// weight prefetch (next nt's loads in flight during current MFMAs); t1 read b128.
__global__ __launch_bounds__(256) void mlp_mfma(const float* __restrict__ hz,
                                                const unsigned short* __restrict__ W1h,
                                                const unsigned short* __restrict__ W1l,
                                                const float* __restrict__ b1,
                                                const unsigned short* __restrict__ W2h,
                                                const unsigned short* __restrict__ W2l,
                                                const float* __restrict__ b2,
                                                float* __restrict__ Z) {
    __shared__ float t1[64][132];  // 528B pitch; b128 reads structurally conflict-free
    int tid = threadIdx.x;
    int w = tid >> 6, l = tid & 63;
    int l15 = l & 15, kg = l >> 4;
    int rbase = blockIdx.x * 64 + w * 16;
    int mrow = rbase + l15;
    const size_t wrow = (size_t)l15 * DIM + kg * 8;  // lane's weight-row offset (+nt*16*DIM)

    // A fragments (hi/lo) for GEMM1, direct from global f32
    bf16x8 ah[4], al[4];
#pragma unroll
    for (int kb = 0; kb < 4; kb++) {
        float buf[8];
        if (mrow < NN) {
            float4 v0 = *(const float4*)(hz + (size_t)mrow * DIM + kb * 32 + kg * 8);
            float4 v1 = *(const float4*)(hz + (size_t)mrow * DIM + kb * 32 + kg * 8 + 4);
            buf[0] = v0.x; buf[1] = v0.y; buf[2] = v0.z; buf[3] = v0.w;
            buf[4] = v1.x; buf[5] = v1.y; buf[6] = v1.z; buf[7] = v1.w;
        } else {
#pragma unroll
            for (int j = 0; j < 8; j++) buf[j] = 0.f;
        }
        split8(buf, ah[kb], al[kb]);
    }

    // GEMM1: t1 = lrelu(hz @ W1 + b1). Double-buffered weights, 3 acc chains.
    bf16x8 whb[2][4], wlb[2][4];
#pragma unroll
    for (int kb = 0; kb < 4; kb++) {
        whb[0][kb] = *(const bf16x8*)(W1h + wrow + (size_t)kb * 32);
        wlb[0][kb] = *(const bf16x8*)(W1l + wrow + (size_t)kb * 32);
    }
#pragma unroll
    for (int nt = 0; nt < 8; nt++) {
        if (nt < 7) {
            size_t nxt = wrow + (size_t)(nt + 1) * 16 * DIM;
#pragma unroll
            for (int kb = 0; kb < 4; kb++) {
                whb[(nt + 1) & 1][kb] = *(const bf16x8*)(W1h + nxt + (size_t)kb * 32);
                wlb[(nt + 1) & 1][kb] = *(const bf16x8*)(W1l + nxt + (size_t)kb * 32);
            }
        }
        f32x4 a0 = {0.f, 0.f, 0.f, 0.f}, a1 = a0, a2 = a0;
#pragma unroll
        for (int kb = 0; kb < 4; kb++) {
            a0 = __builtin_amdgcn_mfma_f32_16x16x32_bf16(ah[kb], whb[nt & 1][kb], a0, 0, 0, 0);
            a1 = __builtin_amdgcn_mfma_f32_16x16x32_bf16(ah[kb], wlb[nt & 1][kb], a1, 0, 0, 0);
            a2 = __builtin_amdgcn_mfma_f32_16x16x32_bf16(al[kb], whb[nt & 1][kb], a2, 0, 0, 0);
        }
        float bias = b1[nt * 16 + l15];
        int colw = nt * 16 + l15;
#pragma unroll
        for (int j = 0; j < 4; j++) {
            t1[w * 16 + kg * 4 + j][colw] = lrelu(a0[j] + a1[j] + a2[j] + bias);
        }
    }

    // Pre-issue GEMM2 nt=0 weights (independent of t1)
#pragma unroll
    for (int kb = 0; kb < 4; kb++) {
        whb[0][kb] = *(const bf16x8*)(W2h + wrow + (size_t)kb * 32);
        wlb[0][kb] = *(const bf16x8*)(W2l + wrow + (size_t)kb * 32);
    }
    // A fragments for GEMM2 from LDS (wave-private rows), b128 reads
    bf16x8 a2h[4], a2l[4];
#pragma unroll
    for (int kb = 0; kb < 4; kb++) {
        float4 q0 = *(const float4*)(&t1[w * 16 + l15][kb * 32 + kg * 8]);
        float4 q1 = *(const float4*)(&t1[w * 16 + l15][kb * 32 + kg * 8 + 4]);
        float buf[8] = {q0.x, q0.y, q0.z, q0.w, q1.x, q1.y, q1.z, q1.w};
        split8(buf, a2h[kb], a2l[kb]);
    }
    // GEMM2: Z = t1 @ W2 + b2. Same double-buffer + 3 chains.
#pragma unroll
    for (int nt = 0; nt < 8; nt++) {
        if (nt < 7) {
            size_t nxt = wrow + (size_t)(nt + 1) * 16 * DIM;
#pragma unroll
            for (int kb = 0; kb < 4; kb++) {
                whb[(nt + 1) & 1][kb] = *(const bf16x8*)(W2h + nxt + (size_t)kb * 32);
                wlb[(nt + 1) & 1][kb] = *(const bf16x8*)(W2l + nxt + (size_t)kb * 32);
            }
        }
        f32x4 a0 = {0.f, 0.f, 0.f, 0.f}, a1 = a0, a2 = a0;
#pragma unroll
        for (int kb = 0; kb < 4; kb++) {
            a0 = __builtin_amdgcn_mfma_f32_16x16x32_bf16(a2h[kb], whb[nt & 1][kb], a0, 0, 0, 0);
            a1 = __builtin_amdgcn_mfma_f32_16x16x32_bf16(a2h[kb], wlb[nt & 1][kb], a1, 0, 0, 0);
            a2 = __builtin_amdgcn_mfma_f32_16x16x32_bf16(a2l[kb], whb[nt & 1][kb], a2, 0, 0, 0);
        }
        float bias = b2[nt * 16 + l15];
#pragma unroll
        for (int j = 0; j < 4; j++) {
            int r = rbase + kg * 4 + j;
            if (r < NN) Z[(size_t)r * DIM + nt * 16 + l15] = a0[j] + a1[j] + a2[j] + bias;
        }
    }
}

// ---------------- BN stats: per-col sum & sumsq
__global__ __launch_bounds__(256) void bnstats_kernel(const float* __restrict__ Z,
                                                      float* __restrict__ stats) {
    int col = threadIdx.x & 127;
    int half = threadIdx.x >> 7;
    int stride = gridDim.x * 2;
    float s = 0.f, s2 = 0.f;
    for (int r = blockIdx.x * 2 + half; r < NN; r += stride) {
        float v = Z[(long long)r * DIM + col];
        s += v;
        s2 += v * v;
    }
    __shared__ float red[2][2][DIM];
    red[0][half][col] = s;
    red[1][half][col] = s2;
    __syncthreads();
    if (half == 0) {
        atomicAdd(&stats[col], red[0][0][col] + red[0][1][col]);
        atomicAdd(&stats[DIM + col], red[1][0][col] + red[1][1][col]);
    }
}

// ---------------- graph start offsets (batch sorted)
__global__ void gstart_kernel(const int* __restrict__ batch, int* __restrict__ gs) {
    int g = threadIdx.x;
    if (g > NGRAPHS) return;
    if (g == NGRAPHS) { gs[g] = NN; return; }
    int lo = 0, hi = NN;
    while (lo < hi) {
        int mid = (lo + hi) >> 1;
        if (batch[mid] < g) lo = mid + 1; else hi = mid;
    }
    gs[g] = lo;
}

// ---------------- gumbel softmax per node with inline BN finalize
__global__ __launch_bounds__(256) void softmaxc_kernel(const float* __restrict__ Z,
                                                       const float* __restrict__ stats,
                                                       const float* __restrict__ gamma,
                                                       const float* __restrict__ beta,
                                                       const float* __restrict__ G,
                                                       float* __restrict__ C) {
    int node = blockIdx.x * 4 + (threadIdx.x >> 6);
    if (node >= NN) return;
    int lane = threadIdx.x & 63;
    int c0 = lane * 2, c1 = lane * 2 + 1;
    float mu0 = stats[c0] * (1.f / NN);
    float mu1 = stats[c1] * (1.f / NN);
    float var0 = stats[DIM + c0] * (1.f / NN) - mu0 * mu0;
    float var1 = stats[DIM + c1] * (1.f / NN) - mu1 * mu1;
    float scx = gamma[c0] * rsqrtf(var0 + BN_EPS);
    float scy = gamma[c1] * rsqrtf(var1 + BN_EPS);
    float shx = beta[c0] - mu0 * scx;
    float shy = beta[c1] - mu1 * scy;
    size_t base = (size_t)node * DIM + lane * 2;
    float2 z = *(const float2*)(Z + base);
    float2 gv = *(const float2*)(G + base);
    float vx = z.x * scx + shx + gv.x;
    float vy = z.y * scy + shy + gv.y;
    float m = fmaxf(vx, vy);
#pragma unroll
    for (int o = 32; o >= 1; o >>= 1) m = fmaxf(m, __shfl_xor(m, o));
    float ex = __expf(vx - m), ey = __expf(vy - m);
    float s = ex + ey;
#pragma unroll
    for (int o = 32; o >= 1; o >>= 1) s += __shfl_xor(s, o);
    float inv = 1.f / s;
    float2 c;
    c.x = ex * inv;
    c.y = ey * inv;
    *(float2*)(C + base) = c;
}

// ---------------- pool: block per graph, contiguous column sums
__global__ __launch_bounds__(128) void pool_kernel(const float* __restrict__ C,
                                                   const int* __restrict__ gs,
                                                   float* __restrict__ pooled) {
    int g = blockIdx.x, col = threadIdx.x;
    int beg = gs[g], end = gs[g + 1];
    float a0 = 0.f, a1 = 0.f, a2 = 0.f, a3 = 0.f;
    int r = beg;
    for (; r + 4 <= end; r += 4) {
        a0 += C[(size_t)r * DIM + col];
        a1 += C[(size_t)(r + 1) * DIM + col];
        a2 += C[(size_t)(r + 2) * DIM + col];
        a3 += C[(size_t)(r + 3) * DIM + col];
    }
    for (; r < end; r++) a0 += C[(size_t)r * DIM + col];
    pooled[g * DIM + col] = (a0 + a1) + (a2 + a3);
}

// ---------------- dense head
__global__ __launch_bounds__(128) void head_kernel(const float* __restrict__ pooled,
                                                   const float* __restrict__ Wd1,
                                                   const float* __restrict__ bd1,
                                                   const float* __restrict__ Wd2,
                                                   const float* __restrict__ bd2,
                                                   float* __restrict__ out) {
    int g = blockIdx.x;
    int j = threadIdx.x;
    __shared__ float hid[DIM];
    __shared__ float logits[NCLASSES];
    float acc = bd1[j];
    for (int k = 0; k < DIM; k++) acc += pooled[g * DIM + k] * Wd1[k * DIM + j];
    hid[j] = lrelu(acc);
    __syncthreads();
    if (j < NCLASSES) {
        float a = bd2[j];
        for (int k = 0; k < DIM; k++) a += hid[k] * Wd2[k * NCLASSES + j];
        logits[j] = a;
    }
    __syncthreads();
    if (j == 0) {
        float m = -1e30f;
        for (int c = 0; c < NCLASSES; c++) m = fmaxf(m, logits[c]);
        float s = 0.f, e[NCLASSES];
        for (int c = 0; c < NCLASSES; c++) { e[c] = __expf(logits[c] - m); s += e[c]; }
        float inv = 1.f / s;
        for (int c = 0; c < NCLASSES; c++) out[g * NCLASSES + c] = e[c] * inv;
    }
}

extern "C" void kernel_launch(void* const* d_in, const int* in_sizes, int n_in,
                              void* d_out, int out_size, void* d_ws, size_t ws_size,
                              hipStream_t stream) {
    const float* x = (const float*)d_in[0];
    const int* edges = (const int*)d_in[1];
    const int* batch = (const int*)d_in[2];
    const float* gum = (const float*)d_in[3];
    const float* W1s = (const float*)d_in[4];
    const float* b1s = (const float*)d_in[5];
    const float* W2s = (const float*)d_in[6];
    const float* b2s = (const float*)d_in[7];
    const float* gammas = (const float*)d_in[8];
    const float* betas = (const float*)d_in[9];
    const float* Wd1 = (const float*)d_in[10];
    const float* bd1 = (const float*)d_in[11];
    const float* Wd2 = (const float*)d_in[12];
    const float* bd2 = (const float*)d_in[13];

    float* out = (float*)d_out;
    float* cout = out + NGRAPHS * NCLASSES;

    const size_t ND = (size_t)NN * DIM;
    float* ws = (float*)d_ws;
    float* z = ws;                                   // ND f32 (pre-BN layer output)
    float* hz = z + ND;                              // ND f32 (gather out / MLP in)
    unsigned short* Wh = (unsigned short*)(hz + ND); // 16*16384 bf16 (W^T hi)
    unsigned short* Wl = Wh + 16 * 16384;            // 16*16384 bf16 (W^T lo)
    float* stats8 = (float*)(Wl + 16 * 16384);       // 8 * 2*DIM
    float* pooled = stats8 + NLAYERS * 2 * DIM;      // NGRAPHS*DIM
    int* counts = (int*)(pooled + NGRAPHS * DIM);    // NN
    int* offsets = counts + NN;                      // NN+1
    int* cursor = offsets + NN + 1;                  // NN
    int* csr_src = cursor + NN;                      // NE
    int* gs = csr_src + NE;                          // NGRAPHS+1

    const int MLP_BLOCKS = (NN + 63) / 64;
    const int EDGE_BLOCKS = (NE + 255) / 256;
    const int NODE_BLOCKS = (NN + 3) / 4;

    // ---- CSR build + weight prep (static per launch)
    hipMemsetAsync(counts, 0, NN * sizeof(int), stream);
    degree_kernel<<<EDGE_BLOCKS, 256, 0, stream>>>(edges, counts);
    scan_kernel<<<1, 1024, 0, stream>>>(counts, offsets);
    hipMemcpyAsync(cursor, offsets, NN * sizeof(int), hipMemcpyDeviceToDevice, stream);
    fill_kernel<<<EDGE_BLOCKS, 256, 0, stream>>>(edges, cursor, csr_src);
    wprep_kernel<<<(16 * 16384 + 255) / 256, 256, 0, stream>>>(W1s, W2s, Wh, Wl);

    hipMemsetAsync(stats8, 0, NLAYERS * 2 * DIM * sizeof(float), stream);

    for (int i = 0; i < NLAYERS; i++) {
        const unsigned short* W1h = Wh + (size_t)(2 * i) * 16384;
        const unsigned short* W1l = Wl + (size_t)(2 * i) * 16384;
        const unsigned short* W2h = Wh + (size_t)(2 * i + 1) * 16384;
        const unsigned short* W2l = Wl + (size_t)(2 * i + 1) * 16384;
        const float* b1 = b1s + (size_t)i * DIM;
        const float* b2 = b2s + (size_t)i * DIM;
        float* stats = stats8 + (size_t)i * 2 * DIM;

        if (i == 0)
            gather_kernel<0><<<NODE_BLOCKS, 256, 0, stream>>>(x, nullptr, nullptr, nullptr,
                                                              offsets, csr_src, hz);
        else
            gather_kernel<1><<<NODE_BLOCKS, 256, 0, stream>>>(
                z, stats8 + (size_t)(i - 1) * 2 * DIM, gammas + (size_t)(i - 1) * DIM,
                betas + (size_t)(i - 1) * DIM, offsets, csr_src, hz);
        mlp_mfma<<<MLP_BLOCKS, 256, 0, stream>>>(hz, W1h, W1l, b1, W2h, W2l, b2, z);
        bnstats_kernel<<<512, 256, 0, stream>>>(z, stats);
    }

    gstart_kernel<<<1, 128, 0, stream>>>(batch, gs);
    softmaxc_kernel<<<NODE_BLOCKS, 256, 0, stream>>>(
        z, stats8 + (size_t)(NLAYERS - 1) * 2 * DIM, gammas + (size_t)(NLAYERS - 1) * DIM,
        betas + (size_t)(NLAYERS - 1) * DIM, gum, cout);
    pool_kernel<<<NGRAPHS, 128, 0, stream>>>(cout, gs, pooled);
    head_kernel<<<NGRAPHS, 128, 0, stream>>>(pooled, Wd1, bd1, Wd2, bd2, out);
}

// Round 12
// 1105.446 us; speedup vs baseline: 1.1797x; 1.1797x over previous
//
#include <hip/hip_runtime.h>

#define NN 50000
#define NE 600000
#define DIM 128
#define NLAYERS 8
#define NCLASSES 10
#define NGRAPHS 64
#define BN_EPS 1e-5f
#define SLOPE 0.01f

typedef __attribute__((ext_vector_type(8))) short bf16x8;
typedef __attribute__((ext_vector_type(4))) float f32x4;

__device__ __forceinline__ float lrelu(float v) { return v > 0.f ? v : SLOPE * v; }

__device__ __forceinline__ unsigned short f2bf(float x) {
    unsigned u = __builtin_bit_cast(unsigned, x);
    unsigned r = (u + 0x7FFFu + ((u >> 16) & 1u)) >> 16;
    return (unsigned short)r;
}
__device__ __forceinline__ float bf2f(unsigned short h) {
    return __builtin_bit_cast(float, (unsigned)h << 16);
}
// split x into hi+lo bf16 pair: hi = bf16(x), lo = bf16(x - hi)
__device__ __forceinline__ void split8(const float* __restrict__ p, bf16x8& hi, bf16x8& lo) {
#pragma unroll
    for (int j = 0; j < 8; j++) {
        float x = p[j];
        unsigned short h = f2bf(x);
        hi[j] = (short)h;
        lo[j] = (short)f2bf(x - bf2f(h));
    }
}

// ---------------- CSR build: degree histogram
__global__ __launch_bounds__(256) void degree_kernel(const int* __restrict__ edges,
                                                     int* __restrict__ counts) {
    int e = blockIdx.x * 256 + threadIdx.x;
    if (e >= NE) return;
    atomicAdd(&counts[edges[NE + e]], 1);
}

// ---------------- CSR build: exclusive scan of counts -> offsets (single block)
__global__ __launch_bounds__(1024) void scan_kernel(const int* __restrict__ counts,
                                                    int* __restrict__ offsets) {
    __shared__ int wsum[16];
    __shared__ int carry;
    int lane = threadIdx.x & 63, wid = threadIdx.x >> 6;
    if (threadIdx.x == 0) { carry = 0; offsets[0] = 0; }
    __syncthreads();
    for (int base = 0; base < NN; base += 1024) {
        int i = base + threadIdx.x;
        int v = (i < NN) ? counts[i] : 0;
        int s = v;
#pragma unroll
        for (int o = 1; o < 64; o <<= 1) {
            int t = __shfl_up(s, o);
            if (lane >= o) s += t;
        }
        if (lane == 63) wsum[wid] = s;
        __syncthreads();
        if (wid == 0 && lane < 16) {
            int w = wsum[lane];
            int sw = w;
#pragma unroll
            for (int o = 1; o < 16; o <<= 1) {
                int t = __shfl_up(sw, o);
                if (lane >= o) sw += t;
            }
            wsum[lane] = sw - w;  // exclusive
        }
        __syncthreads();
        int incl = s + wsum[wid] + carry;
        if (i < NN) offsets[i + 1] = incl;
        __syncthreads();
        if (threadIdx.x == 1023) carry = incl;
        __syncthreads();
    }
}

// ---------------- CSR build: fill src lists
__global__ __launch_bounds__(256) void fill_kernel(const int* __restrict__ edges,
                                                   int* __restrict__ cursor,
                                                   int* __restrict__ csr_src) {
    int e = blockIdx.x * 256 + threadIdx.x;
    if (e >= NE) return;
    int d = edges[NE + e];
    int p = atomicAdd(&cursor[d], 1);
    csr_src[p] = edges[e];
}

// ---------------- weight prep: hi/lo bf16 of W^T in FRAGMENT-MAJOR order:
// Wh[mat][nt][kb][lane][j] = bf16(W[k][n]), n = nt*16+(lane&15), k = kb*32+(lane>>4)*8+j
__global__ __launch_bounds__(256) void wprep_kernel(const float* __restrict__ W1s,
                                                    const float* __restrict__ W2s,
                                                    unsigned short* __restrict__ Wh,
                                                    unsigned short* __restrict__ Wl) {
    int gid = blockIdx.x * 256 + threadIdx.x;  // 16 * 16384
    if (gid >= 16 * 16384) return;
    int mat = gid >> 14;
    int idx = gid & 16383;
    int nt = idx >> 11, kb = (idx >> 9) & 3, lane = (idx >> 3) & 63, j = idx & 7;
    int l15 = lane & 15, kg = lane >> 4;
    int n = nt * 16 + l15, k = kb * 32 + kg * 8 + j;
    int layer = mat >> 1, which = mat & 1;
    const float* src = which ? (W2s + (size_t)layer * 16384) : (W1s + (size_t)layer * 16384);
    float x = src[k * DIM + n];
    unsigned short h = f2bf(x);
    Wh[gid] = h;
    Wl[gid] = f2bf(x - bf2f(h));
}

// ---------------- gather (+ inline BN finalize + lrelu of producing layer):
// hz[i] = f(z[i]) + sum_{j in N(i)} f(z[j]);  f = BN ? lrelu(z*sc+sh) : z
// ILP form: lane-parallel index fetch + 4-deep row-load unroll.
template <int BN>
__global__ __launch_bounds__(256) void gather_kernel(const float* __restrict__ Zin,
                                                     const float* __restrict__ stats,
                                                     const float* __restrict__ gamma,
                                                     const float* __restrict__ beta,
                                                     const int* __restrict__ offsets,
                                                     const int* __restrict__ csr_src,
                                                     float* __restrict__ hz) {
    int node = blockIdx.x * 4 + (threadIdx.x >> 6);
    if (node >= NN) return;
    int lane = threadIdx.x & 63;
    size_t coloff = (size_t)lane * 2;
    float scx = 0.f, scy = 0.f, shx = 0.f, shy = 0.f;
    if (BN) {
        int c0 = lane * 2, c1 = lane * 2 + 1;
        float mu0 = stats[c0] * (1.f / NN);
        float mu1 = stats[c1] * (1.f / NN);
        float var0 = stats[DIM + c0] * (1.f / NN) - mu0 * mu0;
        float var1 = stats[DIM + c1] * (1.f / NN) - mu1 * mu1;
        scx = gamma[c0] * rsqrtf(var0 + BN_EPS);
        scy = gamma[c1] * rsqrtf(var1 + BN_EPS);
        shx = beta[c0] - mu0 * scx;
        shy = beta[c1] - mu1 * scy;
    }
    int beg = offsets[node], end = offsets[node + 1];
    float2 v = *(const float2*)(Zin + (size_t)node * DIM + coloff);
    float ax, ay;
    if (BN) { ax = lrelu(v.x * scx + shx); ay = lrelu(v.y * scy + shy); }
    else    { ax = v.x; ay = v.y; }

    for (int base = beg; base < end; base += 64) {
        int cnt = min(64, end - base);
        int myidx = (lane < cnt) ? csr_src[base + lane] : 0;
        int e = 0;
        for (; e + 4 <= cnt; e += 4) {
            int i0 = __shfl(myidx, e);
            int i1 = __shfl(myidx, e + 1);
            int i2 = __shfl(myidx, e + 2);
            int i3 = __shfl(myidx, e + 3);
            float2 w0 = *(const float2*)(Zin + (size_t)i0 * DIM + coloff);
            float2 w1 = *(const float2*)(Zin + (size_t)i1 * DIM + coloff);
            float2 w2 = *(const float2*)(Zin + (size_t)i2 * DIM + coloff);
            float2 w3 = *(const float2*)(Zin + (size_t)i3 * DIM + coloff);
            if (BN) {
                ax += lrelu(w0.x * scx + shx) + lrelu(w1.x * scx + shx) +
                      lrelu(w2.x * scx + shx) + lrelu(w3.x * scx + shx);
                ay += lrelu(w0.y * scy + shy) + lrelu(w1.y * scy + shy) +
                      lrelu(w2.y * scy + shy) + lrelu(w3.y * scy + shy);
            } else {
                ax += (w0.x + w1.x) + (w2.x + w3.x);
                ay += (w0.y + w1.y) + (w2.y + w3.y);
            }
        }
        for (; e < cnt; e++) {
            int i0 = __shfl(myidx, e);
            float2 w = *(const float2*)(Zin + (size_t)i0 * DIM + coloff);
            if (BN) { ax += lrelu(w.x * scx + shx); ay += lrelu(w.y * scy + shy); }
            else    { ax += w.x; ay += w.y; }
        }
    }
    float2 o; o.x = ax; o.y = ay;
    *(float2*)(hz + (size_t)node * DIM + coloff) = o;
}

// ---------------- fused MLP on matrix cores, split-bf16 (3-product) precision.
// v3: weights staged in LDS once per block (fragment-major, conflict-free b128 reads);
// inner loops contain zero global loads. t1 f32 in LDS, wave-private rows.
__global__ __launch_bounds__(256) void mlp_mfma(const float* __restrict__ hz,
                                                const unsigned short* __restrict__ W1h,
                                                const unsigned short* __restrict__ W1l,
                                                const float* __restrict__ b1,
                                                const unsigned short* __restrict__ W2h,
                                                const unsigned short* __restrict__ W2l,
                                                const float* __restrict__ b2,
                                                float* __restrict__ Z) {
    __shared__ unsigned short wlds[2][16384];  // 64 KB weight stage: [0]=hi, [1]=lo
    __shared__ float t1[64][132];              // 33.8 KB; 528B pitch
    int tid = threadIdx.x;
    int w = tid >> 6, l = tid & 63;
    int l15 = l & 15, kg = l >> 4;
    int rbase = blockIdx.x * 64 + w * 16;
    int mrow = rbase + l15;

    // Issue A row loads first (overlap with W1 staging)
    float4 abuf[8];
#pragma unroll
    for (int kb = 0; kb < 4; kb++) {
        if (mrow < NN) {
            abuf[kb * 2]     = *(const float4*)(hz + (size_t)mrow * DIM + kb * 32 + kg * 8);
            abuf[kb * 2 + 1] = *(const float4*)(hz + (size_t)mrow * DIM + kb * 32 + kg * 8 + 4);
        } else {
            abuf[kb * 2] = make_float4(0.f, 0.f, 0.f, 0.f);
            abuf[kb * 2 + 1] = make_float4(0.f, 0.f, 0.f, 0.f);
        }
    }
    // Stage W1 hi/lo (linear 2x32KB copy; frag-major layout)
    {
        const float4* s0 = (const float4*)W1h;
        const float4* s1 = (const float4*)W1l;
        float4* d0 = (float4*)wlds[0];
        float4* d1 = (float4*)wlds[1];
        for (int i = tid; i < 2048; i += 256) { d0[i] = s0[i]; d1[i] = s1[i]; }
    }
    __syncthreads();

    bf16x8 ah[4], al[4];
#pragma unroll
    for (int kb = 0; kb < 4; kb++) {
        float buf[8] = {abuf[kb*2].x, abuf[kb*2].y, abuf[kb*2].z, abuf[kb*2].w,
                        abuf[kb*2+1].x, abuf[kb*2+1].y, abuf[kb*2+1].z, abuf[kb*2+1].w};
        split8(buf, ah[kb], al[kb]);
    }
    // GEMM1: t1 = lrelu(hz @ W1 + b1); weights from LDS (consecutive-lane 16B reads)
#pragma unroll
    for (int nt = 0; nt < 8; nt++) {
        f32x4 a0 = {0.f, 0.f, 0.f, 0.f}, a1 = a0, a2 = a0;
#pragma unroll
        for (int kb = 0; kb < 4; kb++) {
            int off = nt * 2048 + kb * 512 + l * 8;
            bf16x8 wh = *(const bf16x8*)(&wlds[0][off]);
            bf16x8 wl = *(const bf16x8*)(&wlds[1][off]);
            a0 = __builtin_amdgcn_mfma_f32_16x16x32_bf16(ah[kb], wh, a0, 0, 0, 0);
            a1 = __builtin_amdgcn_mfma_f32_16x16x32_bf16(ah[kb], wl, a1, 0, 0, 0);
            a2 = __builtin_amdgcn_mfma_f32_16x16x32_bf16(al[kb], wh, a2, 0, 0, 0);
        }
        float bias = b1[nt * 16 + l15];
        int colw = nt * 16 + l15;
#pragma unroll
        for (int j = 0; j < 4; j++) {
            t1[w * 16 + kg * 4 + j][colw] = lrelu(a0[j] + a1[j] + a2[j] + bias);
        }
    }
    __syncthreads();  // all waves done reading W1 before wlds is overwritten

    // GEMM2 A fragments from own-wave t1 rows (b128 LDS reads)
    bf16x8 a2h[4], a2l[4];
#pragma unroll
    for (int kb = 0; kb < 4; kb++) {
        float4 q0 = *(const float4*)(&t1[w * 16 + l15][kb * 32 + kg * 8]);
        float4 q1 = *(const float4*)(&t1[w * 16 + l15][kb * 32 + kg * 8 + 4]);
        float buf[8] = {q0.x, q0.y, q0.z, q0.w, q1.x, q1.y, q1.z, q1.w};
        split8(buf, a2h[kb], a2l[kb]);
    }
    // Stage W2 hi/lo over W1
    {
        const float4* s0 = (const float4*)W2h;
        const float4* s1 = (const float4*)W2l;
        float4* d0 = (float4*)wlds[0];
        float4* d1 = (float4*)wlds[1];
        for (int i = tid; i < 2048; i += 256) { d0[i] = s0[i]; d1[i] = s1[i]; }
    }
    __syncthreads();
    // GEMM2: Z = t1 @ W2 + b2
#pragma unroll
    for (int nt = 0; nt < 8; nt++) {
        f32x4 a0 = {0.f, 0.f, 0.f, 0.f}, a1 = a0, a2 = a0;
#pragma unroll
        for (int kb = 0; kb < 4; kb++) {
            int off = nt * 2048 + kb * 512 + l * 8;
            bf16x8 wh = *(const bf16x8*)(&wlds[0][off]);
            bf16x8 wl = *(const bf16x8*)(&wlds[1][off]);
            a0 = __builtin_amdgcn_mfma_f32_16x16x32_bf16(a2h[kb], wh, a0, 0, 0, 0);
            a1 = __builtin_amdgcn_mfma_f32_16x16x32_bf16(a2h[kb], wl, a1, 0, 0, 0);
            a2 = __builtin_amdgcn_mfma_f32_16x16x32_bf16(a2l[kb], wh, a2, 0, 0, 0);
        }
        float bias = b2[nt * 16 + l15];
#pragma unroll
        for (int j = 0; j < 4; j++) {
            int r = rbase + kg * 4 + j;
            if (r < NN) Z[(size_t)r * DIM + nt * 16 + l15] = a0[j] + a1[j] + a2[j] + bias;
        }
    }
}

// ---------------- BN stats: per-col sum & sumsq
__global__ __launch_bounds__(256) void bnstats_kernel(const float* __restrict__ Z,
                                                      float* __restrict__ stats) {
    int col = threadIdx.x & 127;
    int half = threadIdx.x >> 7;
    int stride = gridDim.x * 2;
    float s = 0.f, s2 = 0.f;
    for (int r = blockIdx.x * 2 + half; r < NN; r += stride) {
        float v = Z[(long long)r * DIM + col];
        s += v;
        s2 += v * v;
    }
    __shared__ float red[2][2][DIM];
    red[0][half][col] = s;
    red[1][half][col] = s2;
    __syncthreads();
    if (half == 0) {
        atomicAdd(&stats[col], red[0][0][col] + red[0][1][col]);
        atomicAdd(&stats[DIM + col], red[1][0][col] + red[1][1][col]);
    }
}

// ---------------- graph start offsets (batch sorted)
__global__ void gstart_kernel(const int* __restrict__ batch, int* __restrict__ gs) {
    int g = threadIdx.x;
    if (g > NGRAPHS) return;
    if (g == NGRAPHS) { gs[g] = NN; return; }
    int lo = 0, hi = NN;
    while (lo < hi) {
        int mid = (lo + hi) >> 1;
        if (batch[mid] < g) lo = mid + 1; else hi = mid;
    }
    gs[g] = lo;
}

// ---------------- gumbel softmax per node with inline BN finalize
__global__ __launch_bounds__(256) void softmaxc_kernel(const float* __restrict__ Z,
                                                       const float* __restrict__ stats,
                                                       const float* __restrict__ gamma,
                                                       const float* __restrict__ beta,
                                                       const float* __restrict__ G,
                                                       float* __restrict__ C) {
    int node = blockIdx.x * 4 + (threadIdx.x >> 6);
    if (node >= NN) return;
    int lane = threadIdx.x & 63;
    int c0 = lane * 2, c1 = lane * 2 + 1;
    float mu0 = stats[c0] * (1.f / NN);
    float mu1 = stats[c1] * (1.f / NN);
    float var0 = stats[DIM + c0] * (1.f / NN) - mu0 * mu0;
    float var1 = stats[DIM + c1] * (1.f / NN) - mu1 * mu1;
    float scx = gamma[c0] * rsqrtf(var0 + BN_EPS);
    float scy = gamma[c1] * rsqrtf(var1 + BN_EPS);
    float shx = beta[c0] - mu0 * scx;
    float shy = beta[c1] - mu1 * scy;
    size_t base = (size_t)node * DIM + lane * 2;
    float2 z = *(const float2*)(Z + base);
    float2 gv = *(const float2*)(G + base);
    float vx = z.x * scx + shx + gv.x;
    float vy = z.y * scy + shy + gv.y;
    float m = fmaxf(vx, vy);
#pragma unroll
    for (int o = 32; o >= 1; o >>= 1) m = fmaxf(m, __shfl_xor(m, o));
    float ex = __expf(vx - m), ey = __expf(vy - m);
    float s = ex + ey;
#pragma unroll
    for (int o = 32; o >= 1; o >>= 1) s += __shfl_xor(s, o);
    float inv = 1.f / s;
    float2 c;
    c.x = ex * inv;
    c.y = ey * inv;
    *(float2*)(C + base) = c;
}

// ---------------- pool: block per graph, contiguous column sums
__global__ __launch_bounds__(128) void pool_kernel(const float* __restrict__ C,
                                                   const int* __restrict__ gs,
                                                   float* __restrict__ pooled) {
    int g = blockIdx.x, col = threadIdx.x;
    int beg = gs[g], end = gs[g + 1];
    float a0 = 0.f, a1 = 0.f, a2 = 0.f, a3 = 0.f;
    int r = beg;
    for (; r + 4 <= end; r += 4) {
        a0 += C[(size_t)r * DIM + col];
        a1 += C[(size_t)(r + 1) * DIM + col];
        a2 += C[(size_t)(r + 2) * DIM + col];
        a3 += C[(size_t)(r + 3) * DIM + col];
    }
    for (; r < end; r++) a0 += C[(size_t)r * DIM + col];
    pooled[g * DIM + col] = (a0 + a1) + (a2 + a3);
}

// ---------------- dense head
__global__ __launch_bounds__(128) void head_kernel(const float* __restrict__ pooled,
                                                   const float* __restrict__ Wd1,
                                                   const float* __restrict__ bd1,
                                                   const float* __restrict__ Wd2,
                                                   const float* __restrict__ bd2,
                                                   float* __restrict__ out) {
    int g = blockIdx.x;
    int j = threadIdx.x;
    __shared__ float hid[DIM];
    __shared__ float logits[NCLASSES];
    float acc = bd1[j];
    for (int k = 0; k < DIM; k++) acc += pooled[g * DIM + k] * Wd1[k * DIM + j];
    hid[j] = lrelu(acc);
    __syncthreads();
    if (j < NCLASSES) {
        float a = bd2[j];
        for (int k = 0; k < DIM; k++) a += hid[k] * Wd2[k * NCLASSES + j];
        logits[j] = a;
    }
    __syncthreads();
    if (j == 0) {
        float m = -1e30f;
        for (int c = 0; c < NCLASSES; c++) m = fmaxf(m, logits[c]);
        float s = 0.f, e[NCLASSES];
        for (int c = 0; c < NCLASSES; c++) { e[c] = __expf(logits[c] - m); s += e[c]; }
        float inv = 1.f / s;
        for (int c = 0; c < NCLASSES; c++) out[g * NCLASSES + c] = e[c] * inv;
    }
}

extern "C" void kernel_launch(void* const* d_in, const int* in_sizes, int n_in,
                              void* d_out, int out_size, void* d_ws, size_t ws_size,
                              hipStream_t stream) {
    const float* x = (const float*)d_in[0];
    const int* edges = (const int*)d_in[1];
    const int* batch = (const int*)d_in[2];
    const float* gum = (const float*)d_in[3];
    const float* W1s = (const float*)d_in[4];
    const float* b1s = (const float*)d_in[5];
    const float* W2s = (const float*)d_in[6];
    const float* b2s = (const float*)d_in[7];
    const float* gammas = (const float*)d_in[8];
    const float* betas = (const float*)d_in[9];
    const float* Wd1 = (const float*)d_in[10];
    const float* bd1 = (const float*)d_in[11];
    const float* Wd2 = (const float*)d_in[12];
    const float* bd2 = (const float*)d_in[13];

    float* out = (float*)d_out;
    float* cout = out + NGRAPHS * NCLASSES;

    const size_t ND = (size_t)NN * DIM;
    float* ws = (float*)d_ws;
    float* z = ws;                                   // ND f32 (pre-BN layer output)
    float* hz = z + ND;                              // ND f32 (gather out / MLP in)
    unsigned short* Wh = (unsigned short*)(hz + ND); // 16*16384 bf16 (frag-major hi)
    unsigned short* Wl = Wh + 16 * 16384;            // 16*16384 bf16 (frag-major lo)
    float* stats8 = (float*)(Wl + 16 * 16384);       // 8 * 2*DIM
    float* pooled = stats8 + NLAYERS * 2 * DIM;      // NGRAPHS*DIM
    int* counts = (int*)(pooled + NGRAPHS * DIM);    // NN
    int* offsets = counts + NN;                      // NN+1
    int* cursor = offsets + NN + 1;                  // NN
    int* csr_src = cursor + NN;                      // NE
    int* gs = csr_src + NE;                          // NGRAPHS+1

    const int MLP_BLOCKS = (NN + 63) / 64;
    const int EDGE_BLOCKS = (NE + 255) / 256;
    const int NODE_BLOCKS = (NN + 3) / 4;

    // ---- CSR build + weight prep (static per launch)
    hipMemsetAsync(counts, 0, NN * sizeof(int), stream);
    degree_kernel<<<EDGE_BLOCKS, 256, 0, stream>>>(edges, counts);
    scan_kernel<<<1, 1024, 0, stream>>>(counts, offsets);
    hipMemcpyAsync(cursor, offsets, NN * sizeof(int), hipMemcpyDeviceToDevice, stream);
    fill_kernel<<<EDGE_BLOCKS, 256, 0, stream>>>(edges, cursor, csr_src);
    wprep_kernel<<<(16 * 16384 + 255) / 256, 256, 0, stream>>>(W1s, W2s, Wh, Wl);

    hipMemsetAsync(stats8, 0, NLAYERS * 2 * DIM * sizeof(float), stream);

    for (int i = 0; i < NLAYERS; i++) {
        const unsigned short* W1h = Wh + (size_t)(2 * i) * 16384;
        const unsigned short* W1l = Wl + (size_t)(2 * i) * 16384;
        const unsigned short* W2h = Wh + (size_t)(2 * i + 1) * 16384;
        const unsigned short* W2l = Wl + (size_t)(2 * i + 1) * 16384;
        const float* b1 = b1s + (size_t)i * DIM;
        const float* b2 = b2s + (size_t)i * DIM;
        float* stats = stats8 + (size_t)i * 2 * DIM;

        if (i == 0)
            gather_kernel<0><<<NODE_BLOCKS, 256, 0, stream>>>(x, nullptr, nullptr, nullptr,
                                                              offsets, csr_src, hz);
        else
            gather_kernel<1><<<NODE_BLOCKS, 256, 0, stream>>>(
                z, stats8 + (size_t)(i - 1) * 2 * DIM, gammas + (size_t)(i - 1) * DIM,
                betas + (size_t)(i - 1) * DIM, offsets, csr_src, hz);
        mlp_mfma<<<MLP_BLOCKS, 256, 0, stream>>>(hz, W1h, W1l, b1, W2h, W2l, b2, z);
        bnstats_kernel<<<512, 256, 0, stream>>>(z, stats);
    }

    gstart_kernel<<<1, 128, 0, stream>>>(batch, gs);
    softmaxc_kernel<<<NODE_BLOCKS, 256, 0, stream>>>(
        z, stats8 + (size_t)(NLAYERS - 1) * 2 * DIM, gammas + (size_t)(NLAYERS - 1) * DIM,
        betas + (size_t)(NLAYERS - 1) * DIM, gum, cout);
    pool_kernel<<<NGRAPHS, 128, 0, stream>>>(cout, gs, pooled);
    head_kernel<<<NGRAPHS, 128, 0, stream>>>(pooled, Wd1, bd1, Wd2, bd2, out);
}

// Round 13
// 1077.184 us; speedup vs baseline: 1.2106x; 1.0262x over previous
//
#include <hip/hip_runtime.h>

#define NN 50000
#define NE 600000
#define DIM 128
#define NLAYERS 8
#define NCLASSES 10
#define NGRAPHS 64
#define BN_EPS 1e-5f
#define SLOPE 0.01f

typedef __attribute__((ext_vector_type(8))) short bf16x8;
typedef __attribute__((ext_vector_type(4))) float f32x4;

__device__ __forceinline__ float lrelu(float v) { return v > 0.f ? v : SLOPE * v; }

__device__ __forceinline__ unsigned short f2bf(float x) {
    unsigned u = __builtin_bit_cast(unsigned, x);
    unsigned r = (u + 0x7FFFu + ((u >> 16) & 1u)) >> 16;
    return (unsigned short)r;
}
__device__ __forceinline__ float bf2f(unsigned short h) {
    return __builtin_bit_cast(float, (unsigned)h << 16);
}
// split x into hi+lo bf16 pair: hi = bf16(x), lo = bf16(x - hi)
__device__ __forceinline__ void split8(const float* __restrict__ p, bf16x8& hi, bf16x8& lo) {
#pragma unroll
    for (int j = 0; j < 8; j++) {
        float x = p[j];
        unsigned short h = f2bf(x);
        hi[j] = (short)h;
        lo[j] = (short)f2bf(x - bf2f(h));
    }
}

// ---------------- CSR build: degree histogram
__global__ __launch_bounds__(256) void degree_kernel(const int* __restrict__ edges,
                                                     int* __restrict__ counts) {
    int e = blockIdx.x * 256 + threadIdx.x;
    if (e >= NE) return;
    atomicAdd(&counts[edges[NE + e]], 1);
}

// ---------------- CSR build: exclusive scan of counts -> offsets (single block)
__global__ __launch_bounds__(1024) void scan_kernel(const int* __restrict__ counts,
                                                    int* __restrict__ offsets) {
    __shared__ int wsum[16];
    __shared__ int carry;
    int lane = threadIdx.x & 63, wid = threadIdx.x >> 6;
    if (threadIdx.x == 0) { carry = 0; offsets[0] = 0; }
    __syncthreads();
    for (int base = 0; base < NN; base += 1024) {
        int i = base + threadIdx.x;
        int v = (i < NN) ? counts[i] : 0;
        int s = v;
#pragma unroll
        for (int o = 1; o < 64; o <<= 1) {
            int t = __shfl_up(s, o);
            if (lane >= o) s += t;
        }
        if (lane == 63) wsum[wid] = s;
        __syncthreads();
        if (wid == 0 && lane < 16) {
            int w = wsum[lane];
            int sw = w;
#pragma unroll
            for (int o = 1; o < 16; o <<= 1) {
                int t = __shfl_up(sw, o);
                if (lane >= o) sw += t;
            }
            wsum[lane] = sw - w;  // exclusive
        }
        __syncthreads();
        int incl = s + wsum[wid] + carry;
        if (i < NN) offsets[i + 1] = incl;
        __syncthreads();
        if (threadIdx.x == 1023) carry = incl;
        __syncthreads();
    }
}

// ---------------- CSR build: fill src lists
__global__ __launch_bounds__(256) void fill_kernel(const int* __restrict__ edges,
                                                   int* __restrict__ cursor,
                                                   int* __restrict__ csr_src) {
    int e = blockIdx.x * 256 + threadIdx.x;
    if (e >= NE) return;
    int d = edges[NE + e];
    int p = atomicAdd(&cursor[d], 1);
    csr_src[p] = edges[e];
}

// ---------------- weight prep: hi/lo bf16 of W^T in FRAGMENT-MAJOR order:
// Wh[mat][nt][kb][lane][j] = bf16(W[k][n]), n = nt*16+(lane&15), k = kb*32+(lane>>4)*8+j
__global__ __launch_bounds__(256) void wprep_kernel(const float* __restrict__ W1s,
                                                    const float* __restrict__ W2s,
                                                    unsigned short* __restrict__ Wh,
                                                    unsigned short* __restrict__ Wl) {
    int gid = blockIdx.x * 256 + threadIdx.x;  // 16 * 16384
    if (gid >= 16 * 16384) return;
    int mat = gid >> 14;
    int idx = gid & 16383;
    int nt = idx >> 11, kb = (idx >> 9) & 3, lane = (idx >> 3) & 63, j = idx & 7;
    int l15 = lane & 15, kg = lane >> 4;
    int n = nt * 16 + l15, k = kb * 32 + kg * 8 + j;
    int layer = mat >> 1, which = mat & 1;
    const float* src = which ? (W2s + (size_t)layer * 16384) : (W1s + (size_t)layer * 16384);
    float x = src[k * DIM + n];
    unsigned short h = f2bf(x);
    Wh[gid] = h;
    Wl[gid] = f2bf(x - bf2f(h));
}

// ---------------- gather (+ inline BN finalize + lrelu of producing layer):
// hz[i] = f(z[i]) + sum_{j in N(i)} f(z[j]);  f = BN ? lrelu(z*sc+sh) : z
// ILP form: lane-parallel index fetch + 4-deep row-load unroll.
template <int BN>
__global__ __launch_bounds__(256) void gather_kernel(const float* __restrict__ Zin,
                                                     const float* __restrict__ stats,
                                                     const float* __restrict__ gamma,
                                                     const float* __restrict__ beta,
                                                     const int* __restrict__ offsets,
                                                     const int* __restrict__ csr_src,
                                                     float* __restrict__ hz) {
    int node = blockIdx.x * 4 + (threadIdx.x >> 6);
    if (node >= NN) return;
    int lane = threadIdx.x & 63;
    size_t coloff = (size_t)lane * 2;
    float scx = 0.f, scy = 0.f, shx = 0.f, shy = 0.f;
    if (BN) {
        int c0 = lane * 2, c1 = lane * 2 + 1;
        float mu0 = stats[c0] * (1.f / NN);
        float mu1 = stats[c1] * (1.f / NN);
        float var0 = stats[DIM + c0] * (1.f / NN) - mu0 * mu0;
        float var1 = stats[DIM + c1] * (1.f / NN) - mu1 * mu1;
        scx = gamma[c0] * rsqrtf(var0 + BN_EPS);
        scy = gamma[c1] * rsqrtf(var1 + BN_EPS);
        shx = beta[c0] - mu0 * scx;
        shy = beta[c1] - mu1 * scy;
    }
    int beg = offsets[node], end = offsets[node + 1];
    float2 v = *(const float2*)(Zin + (size_t)node * DIM + coloff);
    float ax, ay;
    if (BN) { ax = lrelu(v.x * scx + shx); ay = lrelu(v.y * scy + shy); }
    else    { ax = v.x; ay = v.y; }

    for (int base = beg; base < end; base += 64) {
        int cnt = min(64, end - base);
        int myidx = (lane < cnt) ? csr_src[base + lane] : 0;
        int e = 0;
        for (; e + 4 <= cnt; e += 4) {
            int i0 = __shfl(myidx, e);
            int i1 = __shfl(myidx, e + 1);
            int i2 = __shfl(myidx, e + 2);
            int i3 = __shfl(myidx, e + 3);
            float2 w0 = *(const float2*)(Zin + (size_t)i0 * DIM + coloff);
            float2 w1 = *(const float2*)(Zin + (size_t)i1 * DIM + coloff);
            float2 w2 = *(const float2*)(Zin + (size_t)i2 * DIM + coloff);
            float2 w3 = *(const float2*)(Zin + (size_t)i3 * DIM + coloff);
            if (BN) {
                ax += lrelu(w0.x * scx + shx) + lrelu(w1.x * scx + shx) +
                      lrelu(w2.x * scx + shx) + lrelu(w3.x * scx + shx);
                ay += lrelu(w0.y * scy + shy) + lrelu(w1.y * scy + shy) +
                      lrelu(w2.y * scy + shy) + lrelu(w3.y * scy + shy);
            } else {
                ax += (w0.x + w1.x) + (w2.x + w3.x);
                ay += (w0.y + w1.y) + (w2.y + w3.y);
            }
        }
        for (; e < cnt; e++) {
            int i0 = __shfl(myidx, e);
            float2 w = *(const float2*)(Zin + (size_t)i0 * DIM + coloff);
            if (BN) { ax += lrelu(w.x * scx + shx); ay += lrelu(w.y * scy + shy); }
            else    { ax += w.x; ay += w.y; }
        }
    }
    float2 o; o.x = ax; o.y = ay;
    *(float2*)(hz + (size_t)node * DIM + coloff) = o;
}

// ---------------- fused MLP on matrix cores, split-bf16 (3-product) precision.
// v3: weights staged in LDS once per block (fragment-major, conflict-free b128 reads);
// inner loops contain zero global loads. t1 f32 in LDS, wave-private rows.
__global__ __launch_bounds__(256) void mlp_mfma(const float* __restrict__ hz,
                                                const unsigned short* __restrict__ W1h,
                                                const unsigned short* __restrict__ W1l,
                                                const float* __restrict__ b1,
                                                const unsigned short* __restrict__ W2h,
                                                const unsigned short* __restrict__ W2l,
                                                const float* __restrict__ b2,
                                                float* __restrict__ Z) {
    __shared__ unsigned short wlds[2][16384];  // 64 KB weight stage: [0]=hi, [1]=lo
    __shared__ float t1[64][132];              // 33.8 KB; 528B pitch
    int tid = threadIdx.x;
    int w = tid >> 6, l = tid & 63;
    int l15 = l & 15, kg = l >> 4;
    int rbase = blockIdx.x * 64 + w * 16;
    int mrow = rbase + l15;

    // Issue A row loads first (overlap with W1 staging)
    float4 abuf[8];
#pragma unroll
    for (int kb = 0; kb < 4; kb++) {
        if (mrow < NN) {
            abuf[kb * 2]     = *(const float4*)(hz + (size_t)mrow * DIM + kb * 32 + kg * 8);
            abuf[kb * 2 + 1] = *(const float4*)(hz + (size_t)mrow * DIM + kb * 32 + kg * 8 + 4);
        } else {
            abuf[kb * 2] = make_float4(0.f, 0.f, 0.f, 0.f);
            abuf[kb * 2 + 1] = make_float4(0.f, 0.f, 0.f, 0.f);
        }
    }
    // Stage W1 hi/lo (linear 2x32KB copy; frag-major layout)
    {
        const float4* s0 = (const float4*)W1h;
        const float4* s1 = (const float4*)W1l;
        float4* d0 = (float4*)wlds[0];
        float4* d1 = (float4*)wlds[1];
        for (int i = tid; i < 2048; i += 256) { d0[i] = s0[i]; d1[i] = s1[i]; }
    }
    __syncthreads();

    bf16x8 ah[4], al[4];
#pragma unroll
    for (int kb = 0; kb < 4; kb++) {
        float buf[8] = {abuf[kb*2].x, abuf[kb*2].y, abuf[kb*2].z, abuf[kb*2].w,
                        abuf[kb*2+1].x, abuf[kb*2+1].y, abuf[kb*2+1].z, abuf[kb*2+1].w};
        split8(buf, ah[kb], al[kb]);
    }
    // GEMM1: t1 = lrelu(hz @ W1 + b1); weights from LDS (consecutive-lane 16B reads)
#pragma unroll
    for (int nt = 0; nt < 8; nt++) {
        f32x4 a0 = {0.f, 0.f, 0.f, 0.f}, a1 = a0, a2 = a0;
#pragma unroll
        for (int kb = 0; kb < 4; kb++) {
            int off = nt * 2048 + kb * 512 + l * 8;
            bf16x8 wh = *(const bf16x8*)(&wlds[0][off]);
            bf16x8 wl = *(const bf16x8*)(&wlds[1][off]);
            a0 = __builtin_amdgcn_mfma_f32_16x16x32_bf16(ah[kb], wh, a0, 0, 0, 0);
            a1 = __builtin_amdgcn_mfma_f32_16x16x32_bf16(ah[kb], wl, a1, 0, 0, 0);
            a2 = __builtin_amdgcn_mfma_f32_16x16x32_bf16(al[kb], wh, a2, 0, 0, 0);
        }
        float bias = b1[nt * 16 + l15];
        int colw = nt * 16 + l15;
#pragma unroll
        for (int j = 0; j < 4; j++) {
            t1[w * 16 + kg * 4 + j][colw] = lrelu(a0[j] + a1[j] + a2[j] + bias);
        }
    }
    __syncthreads();  // all waves done reading W1 before wlds is overwritten

    // GEMM2 A fragments from own-wave t1 rows (b128 LDS reads)
    bf16x8 a2h[4], a2l[4];
#pragma unroll
    for (int kb = 0; kb < 4; kb++) {
        float4 q0 = *(const float4*)(&t1[w * 16 + l15][kb * 32 + kg * 8]);
        float4 q1 = *(const float4*)(&t1[w * 16 + l15][kb * 32 + kg * 8 + 4]);
        float buf[8] = {q0.x, q0.y, q0.z, q0.w, q1.x, q1.y, q1.z, q1.w};
        split8(buf, a2h[kb], a2l[kb]);
    }
    // Stage W2 hi/lo over W1
    {
        const float4* s0 = (const float4*)W2h;
        const float4* s1 = (const float4*)W2l;
        float4* d0 = (float4*)wlds[0];
        float4* d1 = (float4*)wlds[1];
        for (int i = tid; i < 2048; i += 256) { d0[i] = s0[i]; d1[i] = s1[i]; }
    }
    __syncthreads();
    // GEMM2: Z = t1 @ W2 + b2
#pragma unroll
    for (int nt = 0; nt < 8; nt++) {
        f32x4 a0 = {0.f, 0.f, 0.f, 0.f}, a1 = a0, a2 = a0;
#pragma unroll
        for (int kb = 0; kb < 4; kb++) {
            int off = nt * 2048 + kb * 512 + l * 8;
            bf16x8 wh = *(const bf16x8*)(&wlds[0][off]);
            bf16x8 wl = *(const bf16x8*)(&wlds[1][off]);
            a0 = __builtin_amdgcn_mfma_f32_16x16x32_bf16(a2h[kb], wh, a0, 0, 0, 0);
            a1 = __builtin_amdgcn_mfma_f32_16x16x32_bf16(a2h[kb], wl, a1, 0, 0, 0);
            a2 = __builtin_amdgcn_mfma_f32_16x16x32_bf16(a2l[kb], wh, a2, 0, 0, 0);
        }
        float bias = b2[nt * 16 + l15];
#pragma unroll
        for (int j = 0; j < 4; j++) {
            int r = rbase + kg * 4 + j;
            if (r < NN) Z[(size_t)r * DIM + nt * 16 + l15] = a0[j] + a1[j] + a2[j] + bias;
        }
    }
}

// ---------------- BN stats: per-col sum & sumsq
__global__ __launch_bounds__(256) void bnstats_kernel(const float* __restrict__ Z,
                                                      float* __restrict__ stats) {
    int col = threadIdx.x & 127;
    int half = threadIdx.x >> 7;
    int stride = gridDim.x * 2;
    float s = 0.f, s2 = 0.f;
    for (int r = blockIdx.x * 2 + half; r < NN; r += stride) {
        float v = Z[(long long)r * DIM + col];
        s += v;
        s2 += v * v;
    }
    __shared__ float red[2][2][DIM];
    red[0][half][col] = s;
    red[1][half][col] = s2;
    __syncthreads();
    if (half == 0) {
        atomicAdd(&stats[col], red[0][0][col] + red[0][1][col]);
        atomicAdd(&stats[DIM + col], red[1][0][col] + red[1][1][col]);
    }
}

// ---------------- gumbel softmax per node with inline BN finalize
__global__ __launch_bounds__(256) void softmaxc_kernel(const float* __restrict__ Z,
                                                       const float* __restrict__ stats,
                                                       const float* __restrict__ gamma,
                                                       const float* __restrict__ beta,
                                                       const float* __restrict__ G,
                                                       float* __restrict__ C) {
    int node = blockIdx.x * 4 + (threadIdx.x >> 6);
    if (node >= NN) return;
    int lane = threadIdx.x & 63;
    int c0 = lane * 2, c1 = lane * 2 + 1;
    float mu0 = stats[c0] * (1.f / NN);
    float mu1 = stats[c1] * (1.f / NN);
    float var0 = stats[DIM + c0] * (1.f / NN) - mu0 * mu0;
    float var1 = stats[DIM + c1] * (1.f / NN) - mu1 * mu1;
    float scx = gamma[c0] * rsqrtf(var0 + BN_EPS);
    float scy = gamma[c1] * rsqrtf(var1 + BN_EPS);
    float shx = beta[c0] - mu0 * scx;
    float shy = beta[c1] - mu1 * scy;
    size_t base = (size_t)node * DIM + lane * 2;
    float2 z = *(const float2*)(Z + base);
    float2 gv = *(const float2*)(G + base);
    float vx = z.x * scx + shx + gv.x;
    float vy = z.y * scy + shy + gv.y;
    float m = fmaxf(vx, vy);
#pragma unroll
    for (int o = 32; o >= 1; o >>= 1) m = fmaxf(m, __shfl_xor(m, o));
    float ex = __expf(vx - m), ey = __expf(vy - m);
    float s = ex + ey;
#pragma unroll
    for (int o = 32; o >= 1; o >>= 1) s += __shfl_xor(s, o);
    float inv = 1.f / s;
    float2 c;
    c.x = ex * inv;
    c.y = ey * inv;
    *(float2*)(C + base) = c;
}

// ---------------- pool v2: block per row-chunk; batch sorted -> flush on graph change
#define POOL_BLOCKS 512
__global__ __launch_bounds__(128) void pool_kernel(const float* __restrict__ C,
                                                   const int* __restrict__ batch,
                                                   float* __restrict__ pooled) {
    int col = threadIdx.x;
    int rpb = (NN + POOL_BLOCKS - 1) / POOL_BLOCKS;
    int r0 = blockIdx.x * rpb;
    int r1 = min(NN, r0 + rpb);
    if (r0 >= NN) return;
    int curg = batch[r0];
    float acc = 0.f;
    for (int r = r0; r < r1; r++) {
        int g = batch[r];
        if (g != curg) {
            atomicAdd(&pooled[curg * DIM + col], acc);
            acc = 0.f;
            curg = g;
        }
        acc += C[(size_t)r * DIM + col];
    }
    atomicAdd(&pooled[curg * DIM + col], acc);
}

// ---------------- dense head
__global__ __launch_bounds__(128) void head_kernel(const float* __restrict__ pooled,
                                                   const float* __restrict__ Wd1,
                                                   const float* __restrict__ bd1,
                                                   const float* __restrict__ Wd2,
                                                   const float* __restrict__ bd2,
                                                   float* __restrict__ out) {
    int g = blockIdx.x;
    int j = threadIdx.x;
    __shared__ float hid[DIM];
    __shared__ float logits[NCLASSES];
    float acc = bd1[j];
    for (int k = 0; k < DIM; k++) acc += pooled[g * DIM + k] * Wd1[k * DIM + j];
    hid[j] = lrelu(acc);
    __syncthreads();
    if (j < NCLASSES) {
        float a = bd2[j];
        for (int k = 0; k < DIM; k++) a += hid[k] * Wd2[k * NCLASSES + j];
        logits[j] = a;
    }
    __syncthreads();
    if (j == 0) {
        float m = -1e30f;
        for (int c = 0; c < NCLASSES; c++) m = fmaxf(m, logits[c]);
        float s = 0.f, e[NCLASSES];
        for (int c = 0; c < NCLASSES; c++) { e[c] = __expf(logits[c] - m); s += e[c]; }
        float inv = 1.f / s;
        for (int c = 0; c < NCLASSES; c++) out[g * NCLASSES + c] = e[c] * inv;
    }
}

extern "C" void kernel_launch(void* const* d_in, const int* in_sizes, int n_in,
                              void* d_out, int out_size, void* d_ws, size_t ws_size,
                              hipStream_t stream) {
    const float* x = (const float*)d_in[0];
    const int* edges = (const int*)d_in[1];
    const int* batch = (const int*)d_in[2];
    const float* gum = (const float*)d_in[3];
    const float* W1s = (const float*)d_in[4];
    const float* b1s = (const float*)d_in[5];
    const float* W2s = (const float*)d_in[6];
    const float* b2s = (const float*)d_in[7];
    const float* gammas = (const float*)d_in[8];
    const float* betas = (const float*)d_in[9];
    const float* Wd1 = (const float*)d_in[10];
    const float* bd1 = (const float*)d_in[11];
    const float* Wd2 = (const float*)d_in[12];
    const float* bd2 = (const float*)d_in[13];

    float* out = (float*)d_out;
    float* cout = out + NGRAPHS * NCLASSES;

    const size_t ND = (size_t)NN * DIM;
    float* ws = (float*)d_ws;
    float* z = ws;                                   // ND f32 (pre-BN layer output)
    float* hz = z + ND;                              // ND f32 (gather out / MLP in)
    unsigned short* Wh = (unsigned short*)(hz + ND); // 16*16384 bf16 (frag-major hi)
    unsigned short* Wl = Wh + 16 * 16384;            // 16*16384 bf16 (frag-major lo)
    float* stats8 = (float*)(Wl + 16 * 16384);       // 8 * 2*DIM
    float* pooled = stats8 + NLAYERS * 2 * DIM;      // NGRAPHS*DIM
    int* counts = (int*)(pooled + NGRAPHS * DIM);    // NN
    int* offsets = counts + NN;                      // NN+1
    int* cursor = offsets + NN + 1;                  // NN
    int* csr_src = cursor + NN;                      // NE

    const int MLP_BLOCKS = (NN + 63) / 64;
    const int EDGE_BLOCKS = (NE + 255) / 256;
    const int NODE_BLOCKS = (NN + 3) / 4;

    // ---- CSR build + weight prep (static per launch)
    hipMemsetAsync(counts, 0, NN * sizeof(int), stream);
    degree_kernel<<<EDGE_BLOCKS, 256, 0, stream>>>(edges, counts);
    scan_kernel<<<1, 1024, 0, stream>>>(counts, offsets);
    hipMemcpyAsync(cursor, offsets, NN * sizeof(int), hipMemcpyDeviceToDevice, stream);
    fill_kernel<<<EDGE_BLOCKS, 256, 0, stream>>>(edges, cursor, csr_src);
    wprep_kernel<<<(16 * 16384 + 255) / 256, 256, 0, stream>>>(W1s, W2s, Wh, Wl);

    hipMemsetAsync(stats8, 0, NLAYERS * 2 * DIM * sizeof(float), stream);

    for (int i = 0; i < NLAYERS; i++) {
        const unsigned short* W1h = Wh + (size_t)(2 * i) * 16384;
        const unsigned short* W1l = Wl + (size_t)(2 * i) * 16384;
        const unsigned short* W2h = Wh + (size_t)(2 * i + 1) * 16384;
        const unsigned short* W2l = Wl + (size_t)(2 * i + 1) * 16384;
        const float* b1 = b1s + (size_t)i * DIM;
        const float* b2 = b2s + (size_t)i * DIM;
        float* stats = stats8 + (size_t)i * 2 * DIM;

        if (i == 0)
            gather_kernel<0><<<NODE_BLOCKS, 256, 0, stream>>>(x, nullptr, nullptr, nullptr,
                                                              offsets, csr_src, hz);
        else
            gather_kernel<1><<<NODE_BLOCKS, 256, 0, stream>>>(
                z, stats8 + (size_t)(i - 1) * 2 * DIM, gammas + (size_t)(i - 1) * DIM,
                betas + (size_t)(i - 1) * DIM, offsets, csr_src, hz);
        mlp_mfma<<<MLP_BLOCKS, 256, 0, stream>>>(hz, W1h, W1l, b1, W2h, W2l, b2, z);
        bnstats_kernel<<<512, 256, 0, stream>>>(z, stats);
    }

    hipMemsetAsync(pooled, 0, NGRAPHS * DIM * sizeof(float), stream);
    softmaxc_kernel<<<NODE_BLOCKS, 256, 0, stream>>>(
        z, stats8 + (size_t)(NLAYERS - 1) * 2 * DIM, gammas + (size_t)(NLAYERS - 1) * DIM,
        betas + (size_t)(NLAYERS - 1) * DIM, gum, cout);
    pool_kernel<<<POOL_BLOCKS, 128, 0, stream>>>(cout, batch, pooled);
    head_kernel<<<NGRAPHS, 128, 0, stream>>>(pooled, Wd1, bd1, Wd2, bd2, out);
}

// Round 14
// 809.838 us; speedup vs baseline: 1.6103x; 1.3301x over previous
//
#include <hip/hip_runtime.h>

#define NN 50000
#define NE 600000
#define DIM 128
#define NLAYERS 8
#define NCLASSES 10
#define NGRAPHS 64
#define BN_EPS 1e-5f
#define SLOPE 0.01f

typedef __attribute__((ext_vector_type(8))) short bf16x8;
typedef __attribute__((ext_vector_type(4))) float f32x4;

__device__ __forceinline__ float lrelu(float v) { return v > 0.f ? v : SLOPE * v; }

__device__ __forceinline__ unsigned short f2bf(float x) {
    unsigned u = __builtin_bit_cast(unsigned, x);
    unsigned r = (u + 0x7FFFu + ((u >> 16) & 1u)) >> 16;
    return (unsigned short)r;
}
__device__ __forceinline__ float bf2f(unsigned short h) {
    return __builtin_bit_cast(float, (unsigned)h << 16);
}
// split 8 floats (two float4) into hi+lo bf16x8
__device__ __forceinline__ void split8v(float4 q0, float4 q1, bf16x8& hi, bf16x8& lo) {
    float buf[8] = {q0.x, q0.y, q0.z, q0.w, q1.x, q1.y, q1.z, q1.w};
#pragma unroll
    for (int j = 0; j < 8; j++) {
        float x = buf[j];
        unsigned short h = f2bf(x);
        hi[j] = (short)h;
        lo[j] = (short)f2bf(x - bf2f(h));
    }
}

// ---------------- CSR build: degree histogram
__global__ __launch_bounds__(256) void degree_kernel(const int* __restrict__ edges,
                                                     int* __restrict__ counts) {
    int e = blockIdx.x * 256 + threadIdx.x;
    if (e >= NE) return;
    atomicAdd(&counts[edges[NE + e]], 1);
}

// ---------------- CSR build: exclusive scan of counts -> offsets (single block)
__global__ __launch_bounds__(1024) void scan_kernel(const int* __restrict__ counts,
                                                    int* __restrict__ offsets) {
    __shared__ int wsum[16];
    __shared__ int carry;
    int lane = threadIdx.x & 63, wid = threadIdx.x >> 6;
    if (threadIdx.x == 0) { carry = 0; offsets[0] = 0; }
    __syncthreads();
    for (int base = 0; base < NN; base += 1024) {
        int i = base + threadIdx.x;
        int v = (i < NN) ? counts[i] : 0;
        int s = v;
#pragma unroll
        for (int o = 1; o < 64; o <<= 1) {
            int t = __shfl_up(s, o);
            if (lane >= o) s += t;
        }
        if (lane == 63) wsum[wid] = s;
        __syncthreads();
        if (wid == 0 && lane < 16) {
            int w = wsum[lane];
            int sw = w;
#pragma unroll
            for (int o = 1; o < 16; o <<= 1) {
                int t = __shfl_up(sw, o);
                if (lane >= o) sw += t;
            }
            wsum[lane] = sw - w;  // exclusive
        }
        __syncthreads();
        int incl = s + wsum[wid] + carry;
        if (i < NN) offsets[i + 1] = incl;
        __syncthreads();
        if (threadIdx.x == 1023) carry = incl;
        __syncthreads();
    }
}

// ---------------- CSR build: fill src lists
__global__ __launch_bounds__(256) void fill_kernel(const int* __restrict__ edges,
                                                   int* __restrict__ cursor,
                                                   int* __restrict__ csr_src) {
    int e = blockIdx.x * 256 + threadIdx.x;
    if (e >= NE) return;
    int d = edges[NE + e];
    int p = atomicAdd(&cursor[d], 1);
    csr_src[p] = edges[e];
}

// ---------------- weight prep: hi/lo bf16 of W^T in FRAGMENT-MAJOR order:
// Wh[mat][nt][kb][lane][j] = bf16(W[k][n]), n = nt*16+(lane&15), k = kb*32+(lane>>4)*8+j
__global__ __launch_bounds__(256) void wprep_kernel(const float* __restrict__ W1s,
                                                    const float* __restrict__ W2s,
                                                    unsigned short* __restrict__ Wh,
                                                    unsigned short* __restrict__ Wl) {
    int gid = blockIdx.x * 256 + threadIdx.x;  // 16 * 16384
    if (gid >= 16 * 16384) return;
    int mat = gid >> 14;
    int idx = gid & 16383;
    int nt = idx >> 11, kb = (idx >> 9) & 3, lane = (idx >> 3) & 63, j = idx & 7;
    int l15 = lane & 15, kg = lane >> 4;
    int n = nt * 16 + l15, k = kb * 32 + kg * 8 + j;
    int layer = mat >> 1, which = mat & 1;
    const float* src = which ? (W2s + (size_t)layer * 16384) : (W1s + (size_t)layer * 16384);
    float x = src[k * DIM + n];
    unsigned short h = f2bf(x);
    Wh[gid] = h;
    Wl[gid] = f2bf(x - bf2f(h));
}

// ---------------- gather (+ inline BN finalize + lrelu of producing layer):
template <int BN>
__global__ __launch_bounds__(256) void gather_kernel(const float* __restrict__ Zin,
                                                     const float* __restrict__ stats,
                                                     const float* __restrict__ gamma,
                                                     const float* __restrict__ beta,
                                                     const int* __restrict__ offsets,
                                                     const int* __restrict__ csr_src,
                                                     float* __restrict__ hz) {
    int node = blockIdx.x * 4 + (threadIdx.x >> 6);
    if (node >= NN) return;
    int lane = threadIdx.x & 63;
    size_t coloff = (size_t)lane * 2;
    float scx = 0.f, scy = 0.f, shx = 0.f, shy = 0.f;
    if (BN) {
        int c0 = lane * 2, c1 = lane * 2 + 1;
        float mu0 = stats[c0] * (1.f / NN);
        float mu1 = stats[c1] * (1.f / NN);
        float var0 = stats[DIM + c0] * (1.f / NN) - mu0 * mu0;
        float var1 = stats[DIM + c1] * (1.f / NN) - mu1 * mu1;
        scx = gamma[c0] * rsqrtf(var0 + BN_EPS);
        scy = gamma[c1] * rsqrtf(var1 + BN_EPS);
        shx = beta[c0] - mu0 * scx;
        shy = beta[c1] - mu1 * scy;
    }
    int beg = offsets[node], end = offsets[node + 1];
    float2 v = *(const float2*)(Zin + (size_t)node * DIM + coloff);
    float ax, ay;
    if (BN) { ax = lrelu(v.x * scx + shx); ay = lrelu(v.y * scy + shy); }
    else    { ax = v.x; ay = v.y; }

    for (int base = beg; base < end; base += 64) {
        int cnt = min(64, end - base);
        int myidx = (lane < cnt) ? csr_src[base + lane] : 0;
        int e = 0;
        for (; e + 4 <= cnt; e += 4) {
            int i0 = __shfl(myidx, e);
            int i1 = __shfl(myidx, e + 1);
            int i2 = __shfl(myidx, e + 2);
            int i3 = __shfl(myidx, e + 3);
            float2 w0 = *(const float2*)(Zin + (size_t)i0 * DIM + coloff);
            float2 w1 = *(const float2*)(Zin + (size_t)i1 * DIM + coloff);
            float2 w2 = *(const float2*)(Zin + (size_t)i2 * DIM + coloff);
            float2 w3 = *(const float2*)(Zin + (size_t)i3 * DIM + coloff);
            if (BN) {
                ax += lrelu(w0.x * scx + shx) + lrelu(w1.x * scx + shx) +
                      lrelu(w2.x * scx + shx) + lrelu(w3.x * scx + shx);
                ay += lrelu(w0.y * scy + shy) + lrelu(w1.y * scy + shy) +
                      lrelu(w2.y * scy + shy) + lrelu(w3.y * scy + shy);
            } else {
                ax += (w0.x + w1.x) + (w2.x + w3.x);
                ay += (w0.y + w1.y) + (w2.y + w3.y);
            }
        }
        for (; e < cnt; e++) {
            int i0 = __shfl(myidx, e);
            float2 w = *(const float2*)(Zin + (size_t)i0 * DIM + coloff);
            if (BN) { ax += lrelu(w.x * scx + shx); ay += lrelu(w.y * scy + shy); }
            else    { ax += w.x; ay += w.y; }
        }
    }
    float2 o; o.x = ax; o.y = ay;
    *(float2*)(hz + (size_t)node * DIM + coloff) = o;
}

// ---------------- fused MLP v4: all 4 weight mats staged once (128 KB LDS),
// 256 rows/block in 4 barrier-free slabs (t1 rows wave-private), swizzled t1,
// BN stats accumulated in-register + one block-level reduction (replaces bnstats).
// LDS: 128 KB weights + 32 KB t1 = 160 KiB exactly -> 1 block/CU, 196 blocks (1 gen).
__device__ __forceinline__ int t1idx(int row, int col) {
    return (row * 128 + col) ^ ((row & 7) << 2);  // f32 units; XOR = byte ^ ((row&7)<<4)
}

__global__ __launch_bounds__(256) void mlp_mfma(const float* __restrict__ hz,
                                                const unsigned short* __restrict__ W1h,
                                                const unsigned short* __restrict__ W1l,
                                                const float* __restrict__ b1,
                                                const unsigned short* __restrict__ W2h,
                                                const unsigned short* __restrict__ W2l,
                                                const float* __restrict__ b2,
                                                float* __restrict__ Z,
                                                float* __restrict__ stats) {
    __shared__ unsigned short wlds[4][16384];  // 128 KB: W1h, W1l, W2h, W2l (frag-major)
    __shared__ float t1s[8192];                // 32 KB swizzled [64][128]
    int tid = threadIdx.x;
    int w = tid >> 6, l = tid & 63;
    int l15 = l & 15, kg = l >> 4;

    // bias regs (global loads before barrier)
    float bias1[8], bias2[8];
#pragma unroll
    for (int nt = 0; nt < 8; nt++) {
        bias1[nt] = b1[nt * 16 + l15];
        bias2[nt] = b2[nt * 16 + l15];
    }
    // stage all four weight matrices
    {
        const float4* s0 = (const float4*)W1h;
        const float4* s1 = (const float4*)W1l;
        const float4* s2 = (const float4*)W2h;
        const float4* s3 = (const float4*)W2l;
        float4* d0 = (float4*)wlds[0];
        float4* d1 = (float4*)wlds[1];
        float4* d2 = (float4*)wlds[2];
        float4* d3 = (float4*)wlds[3];
        for (int i = tid; i < 2048; i += 256) {
            d0[i] = s0[i]; d1[i] = s1[i]; d2[i] = s2[i]; d3[i] = s3[i];
        }
    }
    __syncthreads();

    float sacc[8], s2acc[8];
#pragma unroll
    for (int nt = 0; nt < 8; nt++) { sacc[nt] = 0.f; s2acc[nt] = 0.f; }

    int blk0 = blockIdx.x * 256;
    // preload slab 0 A rows
    float4 abuf[8];
    {
        int mrow = blk0 + w * 16 + l15;
#pragma unroll
        for (int kb = 0; kb < 4; kb++) {
            if (mrow < NN) {
                abuf[kb * 2]     = *(const float4*)(hz + (size_t)mrow * DIM + kb * 32 + kg * 8);
                abuf[kb * 2 + 1] = *(const float4*)(hz + (size_t)mrow * DIM + kb * 32 + kg * 8 + 4);
            } else {
                abuf[kb * 2] = make_float4(0.f, 0.f, 0.f, 0.f);
                abuf[kb * 2 + 1] = make_float4(0.f, 0.f, 0.f, 0.f);
            }
        }
    }

#pragma unroll
    for (int slab = 0; slab < 4; slab++) {
        bf16x8 ah[4], al[4];
#pragma unroll
        for (int kb = 0; kb < 4; kb++) split8v(abuf[kb * 2], abuf[kb * 2 + 1], ah[kb], al[kb]);
        // prefetch next slab's A rows (in flight during GEMM work, no barriers)
        if (slab < 3) {
            int mrow = blk0 + (slab + 1) * 64 + w * 16 + l15;
#pragma unroll
            for (int kb = 0; kb < 4; kb++) {
                if (mrow < NN) {
                    abuf[kb * 2]     = *(const float4*)(hz + (size_t)mrow * DIM + kb * 32 + kg * 8);
                    abuf[kb * 2 + 1] = *(const float4*)(hz + (size_t)mrow * DIM + kb * 32 + kg * 8 + 4);
                } else {
                    abuf[kb * 2] = make_float4(0.f, 0.f, 0.f, 0.f);
                    abuf[kb * 2 + 1] = make_float4(0.f, 0.f, 0.f, 0.f);
                }
            }
        }
        // GEMM1: t1 = lrelu(hz @ W1 + b1); weights from LDS
#pragma unroll
        for (int nt = 0; nt < 8; nt++) {
            f32x4 a0 = {0.f, 0.f, 0.f, 0.f}, a1 = a0, a2 = a0;
#pragma unroll
            for (int kb = 0; kb < 4; kb++) {
                int off = nt * 2048 + kb * 512 + l * 8;
                bf16x8 wh = *(const bf16x8*)(&wlds[0][off]);
                bf16x8 wl = *(const bf16x8*)(&wlds[1][off]);
                a0 = __builtin_amdgcn_mfma_f32_16x16x32_bf16(ah[kb], wh, a0, 0, 0, 0);
                a1 = __builtin_amdgcn_mfma_f32_16x16x32_bf16(ah[kb], wl, a1, 0, 0, 0);
                a2 = __builtin_amdgcn_mfma_f32_16x16x32_bf16(al[kb], wh, a2, 0, 0, 0);
            }
            int colw = nt * 16 + l15;
#pragma unroll
            for (int j = 0; j < 4; j++) {
                t1s[t1idx(w * 16 + kg * 4 + j, colw)] = lrelu(a0[j] + a1[j] + a2[j] + bias1[nt]);
            }
        }
        // read own t1 rows (wave-private; compiler inserts lgkmcnt waits)
        bf16x8 a2h[4], a2l[4];
#pragma unroll
        for (int kb = 0; kb < 4; kb++) {
            int c = kb * 32 + kg * 8;
            float4 q0 = *(const float4*)(&t1s[t1idx(w * 16 + l15, c)]);
            float4 q1 = *(const float4*)(&t1s[t1idx(w * 16 + l15, c + 4)]);
            split8v(q0, q1, a2h[kb], a2l[kb]);
        }
        // GEMM2: Z = t1 @ W2 + b2, with in-register BN stats
#pragma unroll
        for (int nt = 0; nt < 8; nt++) {
            f32x4 a0 = {0.f, 0.f, 0.f, 0.f}, a1 = a0, a2 = a0;
#pragma unroll
            for (int kb = 0; kb < 4; kb++) {
                int off = nt * 2048 + kb * 512 + l * 8;
                bf16x8 wh = *(const bf16x8*)(&wlds[2][off]);
                bf16x8 wl = *(const bf16x8*)(&wlds[3][off]);
                a0 = __builtin_amdgcn_mfma_f32_16x16x32_bf16(a2h[kb], wh, a0, 0, 0, 0);
                a1 = __builtin_amdgcn_mfma_f32_16x16x32_bf16(a2h[kb], wl, a1, 0, 0, 0);
                a2 = __builtin_amdgcn_mfma_f32_16x16x32_bf16(a2l[kb], wh, a2, 0, 0, 0);
            }
#pragma unroll
            for (int j = 0; j < 4; j++) {
                int r = blk0 + slab * 64 + w * 16 + kg * 4 + j;
                if (r < NN) {
                    float o = a0[j] + a1[j] + a2[j] + bias2[nt];
                    Z[(size_t)r * DIM + nt * 16 + l15] = o;
                    sacc[nt] += o;
                    s2acc[nt] += o * o;
                }
            }
        }
    }

    // block-level stats reduction (reuse t1s)
    __syncthreads();
    int part = w * 4 + kg;  // 0..15
#pragma unroll
    for (int nt = 0; nt < 8; nt++) {
        t1s[part * 128 + nt * 16 + l15] = sacc[nt];
        t1s[2048 + part * 128 + nt * 16 + l15] = s2acc[nt];
    }
    __syncthreads();
    if (tid < DIM) {
        float ts = 0.f, ts2 = 0.f;
#pragma unroll
        for (int p = 0; p < 16; p++) {
            ts += t1s[p * 128 + tid];
            ts2 += t1s[2048 + p * 128 + tid];
        }
        atomicAdd(&stats[tid], ts);
        atomicAdd(&stats[DIM + tid], ts2);
    }
}

// ---------------- gumbel softmax per node with inline BN finalize
__global__ __launch_bounds__(256) void softmaxc_kernel(const float* __restrict__ Z,
                                                       const float* __restrict__ stats,
                                                       const float* __restrict__ gamma,
                                                       const float* __restrict__ beta,
                                                       const float* __restrict__ G,
                                                       float* __restrict__ C) {
    int node = blockIdx.x * 4 + (threadIdx.x >> 6);
    if (node >= NN) return;
    int lane = threadIdx.x & 63;
    int c0 = lane * 2, c1 = lane * 2 + 1;
    float mu0 = stats[c0] * (1.f / NN);
    float mu1 = stats[c1] * (1.f / NN);
    float var0 = stats[DIM + c0] * (1.f / NN) - mu0 * mu0;
    float var1 = stats[DIM + c1] * (1.f / NN) - mu1 * mu1;
    float scx = gamma[c0] * rsqrtf(var0 + BN_EPS);
    float scy = gamma[c1] * rsqrtf(var1 + BN_EPS);
    float shx = beta[c0] - mu0 * scx;
    float shy = beta[c1] - mu1 * scy;
    size_t base = (size_t)node * DIM + lane * 2;
    float2 z = *(const float2*)(Z + base);
    float2 gv = *(const float2*)(G + base);
    float vx = z.x * scx + shx + gv.x;
    float vy = z.y * scy + shy + gv.y;
    float m = fmaxf(vx, vy);
#pragma unroll
    for (int o = 32; o >= 1; o >>= 1) m = fmaxf(m, __shfl_xor(m, o));
    float ex = __expf(vx - m), ey = __expf(vy - m);
    float s = ex + ey;
#pragma unroll
    for (int o = 32; o >= 1; o >>= 1) s += __shfl_xor(s, o);
    float inv = 1.f / s;
    float2 c;
    c.x = ex * inv;
    c.y = ey * inv;
    *(float2*)(C + base) = c;
}

// ---------------- pool v2: block per row-chunk; batch sorted -> flush on graph change
#define POOL_BLOCKS 512
__global__ __launch_bounds__(128) void pool_kernel(const float* __restrict__ C,
                                                   const int* __restrict__ batch,
                                                   float* __restrict__ pooled) {
    int col = threadIdx.x;
    int rpb = (NN + POOL_BLOCKS - 1) / POOL_BLOCKS;
    int r0 = blockIdx.x * rpb;
    int r1 = min(NN, r0 + rpb);
    if (r0 >= NN) return;
    int curg = batch[r0];
    float acc = 0.f;
    for (int r = r0; r < r1; r++) {
        int g = batch[r];
        if (g != curg) {
            atomicAdd(&pooled[curg * DIM + col], acc);
            acc = 0.f;
            curg = g;
        }
        acc += C[(size_t)r * DIM + col];
    }
    atomicAdd(&pooled[curg * DIM + col], acc);
}

// ---------------- dense head
__global__ __launch_bounds__(128) void head_kernel(const float* __restrict__ pooled,
                                                   const float* __restrict__ Wd1,
                                                   const float* __restrict__ bd1,
                                                   const float* __restrict__ Wd2,
                                                   const float* __restrict__ bd2,
                                                   float* __restrict__ out) {
    int g = blockIdx.x;
    int j = threadIdx.x;
    __shared__ float hid[DIM];
    __shared__ float logits[NCLASSES];
    float acc = bd1[j];
    for (int k = 0; k < DIM; k++) acc += pooled[g * DIM + k] * Wd1[k * DIM + j];
    hid[j] = lrelu(acc);
    __syncthreads();
    if (j < NCLASSES) {
        float a = bd2[j];
        for (int k = 0; k < DIM; k++) a += hid[k] * Wd2[k * NCLASSES + j];
        logits[j] = a;
    }
    __syncthreads();
    if (j == 0) {
        float m = -1e30f;
        for (int c = 0; c < NCLASSES; c++) m = fmaxf(m, logits[c]);
        float s = 0.f, e[NCLASSES];
        for (int c = 0; c < NCLASSES; c++) { e[c] = __expf(logits[c] - m); s += e[c]; }
        float inv = 1.f / s;
        for (int c = 0; c < NCLASSES; c++) out[g * NCLASSES + c] = e[c] * inv;
    }
}

extern "C" void kernel_launch(void* const* d_in, const int* in_sizes, int n_in,
                              void* d_out, int out_size, void* d_ws, size_t ws_size,
                              hipStream_t stream) {
    const float* x = (const float*)d_in[0];
    const int* edges = (const int*)d_in[1];
    const int* batch = (const int*)d_in[2];
    const float* gum = (const float*)d_in[3];
    const float* W1s = (const float*)d_in[4];
    const float* b1s = (const float*)d_in[5];
    const float* W2s = (const float*)d_in[6];
    const float* b2s = (const float*)d_in[7];
    const float* gammas = (const float*)d_in[8];
    const float* betas = (const float*)d_in[9];
    const float* Wd1 = (const float*)d_in[10];
    const float* bd1 = (const float*)d_in[11];
    const float* Wd2 = (const float*)d_in[12];
    const float* bd2 = (const float*)d_in[13];

    float* out = (float*)d_out;
    float* cout = out + NGRAPHS * NCLASSES;

    const size_t ND = (size_t)NN * DIM;
    float* ws = (float*)d_ws;
    float* z = ws;                                   // ND f32 (pre-BN layer output)
    float* hz = z + ND;                              // ND f32 (gather out / MLP in)
    unsigned short* Wh = (unsigned short*)(hz + ND); // 16*16384 bf16 (frag-major hi)
    unsigned short* Wl = Wh + 16 * 16384;            // 16*16384 bf16 (frag-major lo)
    float* stats8 = (float*)(Wl + 16 * 16384);       // 8 * 2*DIM
    float* pooled = stats8 + NLAYERS * 2 * DIM;      // NGRAPHS*DIM
    int* counts = (int*)(pooled + NGRAPHS * DIM);    // NN
    int* offsets = counts + NN;                      // NN+1
    int* cursor = offsets + NN + 1;                  // NN
    int* csr_src = cursor + NN;                      // NE

    const int MLP_BLOCKS = (NN + 255) / 256;  // 196 blocks, 256 rows each
    const int EDGE_BLOCKS = (NE + 255) / 256;
    const int NODE_BLOCKS = (NN + 3) / 4;

    // ---- CSR build + weight prep (static per launch)
    hipMemsetAsync(counts, 0, NN * sizeof(int), stream);
    degree_kernel<<<EDGE_BLOCKS, 256, 0, stream>>>(edges, counts);
    scan_kernel<<<1, 1024, 0, stream>>>(counts, offsets);
    hipMemcpyAsync(cursor, offsets, NN * sizeof(int), hipMemcpyDeviceToDevice, stream);
    fill_kernel<<<EDGE_BLOCKS, 256, 0, stream>>>(edges, cursor, csr_src);
    wprep_kernel<<<(16 * 16384 + 255) / 256, 256, 0, stream>>>(W1s, W2s, Wh, Wl);

    hipMemsetAsync(stats8, 0, NLAYERS * 2 * DIM * sizeof(float), stream);

    for (int i = 0; i < NLAYERS; i++) {
        const unsigned short* W1h = Wh + (size_t)(2 * i) * 16384;
        const unsigned short* W1l = Wl + (size_t)(2 * i) * 16384;
        const unsigned short* W2h = Wh + (size_t)(2 * i + 1) * 16384;
        const unsigned short* W2l = Wl + (size_t)(2 * i + 1) * 16384;
        const float* b1 = b1s + (size_t)i * DIM;
        const float* b2 = b2s + (size_t)i * DIM;
        float* stats = stats8 + (size_t)i * 2 * DIM;

        if (i == 0)
            gather_kernel<0><<<NODE_BLOCKS, 256, 0, stream>>>(x, nullptr, nullptr, nullptr,
                                                              offsets, csr_src, hz);
        else
            gather_kernel<1><<<NODE_BLOCKS, 256, 0, stream>>>(
                z, stats8 + (size_t)(i - 1) * 2 * DIM, gammas + (size_t)(i - 1) * DIM,
                betas + (size_t)(i - 1) * DIM, offsets, csr_src, hz);
        mlp_mfma<<<MLP_BLOCKS, 256, 0, stream>>>(hz, W1h, W1l, b1, W2h, W2l, b2, z, stats);
    }

    hipMemsetAsync(pooled, 0, NGRAPHS * DIM * sizeof(float), stream);
    softmaxc_kernel<<<NODE_BLOCKS, 256, 0, stream>>>(
        z, stats8 + (size_t)(NLAYERS - 1) * 2 * DIM, gammas + (size_t)(NLAYERS - 1) * DIM,
        betas + (size_t)(NLAYERS - 1) * DIM, gum, cout);
    pool_kernel<<<POOL_BLOCKS, 128, 0, stream>>>(cout, batch, pooled);
    head_kernel<<<NGRAPHS, 128, 0, stream>>>(pooled, Wd1, bd1, Wd2, bd2, out);
}

// Round 15
// 657.169 us; speedup vs baseline: 1.9844x; 1.2323x over previous
//
#include <hip/hip_runtime.h>

#define NN 50000
#define NE 600000
#define DIM 128
#define NLAYERS 8
#define NCLASSES 10
#define NGRAPHS 64
#define BN_EPS 1e-5f
#define SLOPE 0.01f

typedef __attribute__((ext_vector_type(8))) short bf16x8;
typedef __attribute__((ext_vector_type(4))) float f32x4;

__device__ __forceinline__ float lrelu(float v) { return v > 0.f ? v : SLOPE * v; }

__device__ __forceinline__ unsigned short f2bf(float x) {
    unsigned u = __builtin_bit_cast(unsigned, x);
    unsigned r = (u + 0x7FFFu + ((u >> 16) & 1u)) >> 16;
    return (unsigned short)r;
}
__device__ __forceinline__ float bf2f(unsigned short h) {
    return __builtin_bit_cast(float, (unsigned)h << 16);
}
// split 8 floats (two float4) into hi+lo bf16x8
__device__ __forceinline__ void split8v(float4 q0, float4 q1, bf16x8& hi, bf16x8& lo) {
    float buf[8] = {q0.x, q0.y, q0.z, q0.w, q1.x, q1.y, q1.z, q1.w};
#pragma unroll
    for (int j = 0; j < 8; j++) {
        float x = buf[j];
        unsigned short h = f2bf(x);
        hi[j] = (short)h;
        lo[j] = (short)f2bf(x - bf2f(h));
    }
}

// ---------------- CSR build: degree histogram
__global__ __launch_bounds__(256) void degree_kernel(const int* __restrict__ edges,
                                                     int* __restrict__ counts) {
    int e = blockIdx.x * 256 + threadIdx.x;
    if (e >= NE) return;
    atomicAdd(&counts[edges[NE + e]], 1);
}

// ---------------- hierarchical scan (replaces 46us single-block scan)
#define SCAN_BLOCKS ((NN + 255) / 256)
__global__ __launch_bounds__(256) void psum_kernel(const int* __restrict__ counts,
                                                   int* __restrict__ psums) {
    __shared__ int red[256];
    int i = blockIdx.x * 256 + threadIdx.x;
    red[threadIdx.x] = (i < NN) ? counts[i] : 0;
    __syncthreads();
    for (int s = 128; s > 0; s >>= 1) {
        if (threadIdx.x < s) red[threadIdx.x] += red[threadIdx.x + s];
        __syncthreads();
    }
    if (threadIdx.x == 0) psums[blockIdx.x] = red[0];
}
__global__ __launch_bounds__(256) void pscan_kernel(int* __restrict__ psums) {
    __shared__ int buf[256];
    int t = threadIdx.x;
    buf[t] = (t < SCAN_BLOCKS) ? psums[t] : 0;
    __syncthreads();
    for (int o = 1; o < 256; o <<= 1) {
        int v = (t >= o) ? buf[t - o] : 0;
        __syncthreads();
        buf[t] += v;
        __syncthreads();
    }
    if (t < SCAN_BLOCKS) psums[t] = (t == 0) ? 0 : buf[t - 1];  // exclusive
}
__global__ __launch_bounds__(256) void owrite_kernel(const int* __restrict__ counts,
                                                     const int* __restrict__ psums,
                                                     int* __restrict__ offsets) {
    int b = blockIdx.x, t = threadIdx.x;
    int i = b * 256 + t;
    __shared__ int buf[256];
    buf[t] = (i < NN) ? counts[i] : 0;
    __syncthreads();
    for (int o = 1; o < 256; o <<= 1) {
        int u = (t >= o) ? buf[t - o] : 0;
        __syncthreads();
        buf[t] += u;
        __syncthreads();
    }
    if (i < NN) offsets[i + 1] = psums[b] + buf[t];  // inclusive within block + base
    if (i == 0) offsets[0] = 0;
}

// ---------------- CSR build: fill src lists
__global__ __launch_bounds__(256) void fill_kernel(const int* __restrict__ edges,
                                                   int* __restrict__ cursor,
                                                   int* __restrict__ csr_src) {
    int e = blockIdx.x * 256 + threadIdx.x;
    if (e >= NE) return;
    int d = edges[NE + e];
    int p = atomicAdd(&cursor[d], 1);
    csr_src[p] = edges[e];
}

// ---------------- weight prep: hi/lo bf16 of W^T in FRAGMENT-MAJOR order
__global__ __launch_bounds__(256) void wprep_kernel(const float* __restrict__ W1s,
                                                    const float* __restrict__ W2s,
                                                    unsigned short* __restrict__ Wh,
                                                    unsigned short* __restrict__ Wl) {
    int gid = blockIdx.x * 256 + threadIdx.x;  // 16 * 16384
    if (gid >= 16 * 16384) return;
    int mat = gid >> 14;
    int idx = gid & 16383;
    int nt = idx >> 11, kb = (idx >> 9) & 3, lane = (idx >> 3) & 63, j = idx & 7;
    int l15 = lane & 15, kg = lane >> 4;
    int n = nt * 16 + l15, k = kb * 32 + kg * 8 + j;
    int layer = mat >> 1, which = mat & 1;
    const float* src = which ? (W2s + (size_t)layer * 16384) : (W1s + (size_t)layer * 16384);
    float x = src[k * DIM + n];
    unsigned short h = f2bf(x);
    Wh[gid] = h;
    Wl[gid] = f2bf(x - bf2f(h));
}

// ---------------- gather (+ inline BN finalize + lrelu of producing layer):
// BN=0: Zin = x (f32). BN=1: Zin = zb (bf16 rows, half the read bytes).
template <int BN>
__global__ __launch_bounds__(256) void gather_kernel(const void* __restrict__ Zin,
                                                     const float* __restrict__ stats,
                                                     const float* __restrict__ gamma,
                                                     const float* __restrict__ beta,
                                                     const int* __restrict__ offsets,
                                                     const int* __restrict__ csr_src,
                                                     float* __restrict__ hz) {
    int node = blockIdx.x * 4 + (threadIdx.x >> 6);
    if (node >= NN) return;
    int lane = threadIdx.x & 63;
    float scx = 0.f, scy = 0.f, shx = 0.f, shy = 0.f;
    if (BN) {
        int c0 = lane * 2, c1 = lane * 2 + 1;
        float mu0 = stats[c0] * (1.f / NN);
        float mu1 = stats[c1] * (1.f / NN);
        float var0 = stats[DIM + c0] * (1.f / NN) - mu0 * mu0;
        float var1 = stats[DIM + c1] * (1.f / NN) - mu1 * mu1;
        scx = gamma[c0] * rsqrtf(var0 + BN_EPS);
        scy = gamma[c1] * rsqrtf(var1 + BN_EPS);
        shx = beta[c0] - mu0 * scx;
        shy = beta[c1] - mu1 * scy;
    }
    int beg = offsets[node], end = offsets[node + 1];
    float ax, ay;
    if (BN) {
        const unsigned* zrow = (const unsigned*)((const unsigned short*)Zin + (size_t)node * DIM);
        unsigned p = zrow[lane];
        ax = lrelu(bf2f((unsigned short)p) * scx + shx);
        ay = lrelu(bf2f((unsigned short)(p >> 16)) * scy + shy);
    } else {
        float2 v = *(const float2*)((const float*)Zin + (size_t)node * DIM + lane * 2);
        ax = v.x; ay = v.y;
    }

    for (int base = beg; base < end; base += 64) {
        int cnt = min(64, end - base);
        int myidx = (lane < cnt) ? csr_src[base + lane] : 0;
        int e = 0;
        for (; e + 4 <= cnt; e += 4) {
            int i0 = __shfl(myidx, e);
            int i1 = __shfl(myidx, e + 1);
            int i2 = __shfl(myidx, e + 2);
            int i3 = __shfl(myidx, e + 3);
            if (BN) {
                const unsigned short* zb = (const unsigned short*)Zin;
                unsigned p0 = ((const unsigned*)(zb + (size_t)i0 * DIM))[lane];
                unsigned p1 = ((const unsigned*)(zb + (size_t)i1 * DIM))[lane];
                unsigned p2 = ((const unsigned*)(zb + (size_t)i2 * DIM))[lane];
                unsigned p3 = ((const unsigned*)(zb + (size_t)i3 * DIM))[lane];
                ax += lrelu(bf2f((unsigned short)p0) * scx + shx) +
                      lrelu(bf2f((unsigned short)p1) * scx + shx) +
                      lrelu(bf2f((unsigned short)p2) * scx + shx) +
                      lrelu(bf2f((unsigned short)p3) * scx + shx);
                ay += lrelu(bf2f((unsigned short)(p0 >> 16)) * scy + shy) +
                      lrelu(bf2f((unsigned short)(p1 >> 16)) * scy + shy) +
                      lrelu(bf2f((unsigned short)(p2 >> 16)) * scy + shy) +
                      lrelu(bf2f((unsigned short)(p3 >> 16)) * scy + shy);
            } else {
                const float* zf = (const float*)Zin;
                float2 w0 = *(const float2*)(zf + (size_t)i0 * DIM + lane * 2);
                float2 w1 = *(const float2*)(zf + (size_t)i1 * DIM + lane * 2);
                float2 w2 = *(const float2*)(zf + (size_t)i2 * DIM + lane * 2);
                float2 w3 = *(const float2*)(zf + (size_t)i3 * DIM + lane * 2);
                ax += (w0.x + w1.x) + (w2.x + w3.x);
                ay += (w0.y + w1.y) + (w2.y + w3.y);
            }
        }
        for (; e < cnt; e++) {
            int i0 = __shfl(myidx, e);
            if (BN) {
                unsigned p = ((const unsigned*)((const unsigned short*)Zin + (size_t)i0 * DIM))[lane];
                ax += lrelu(bf2f((unsigned short)p) * scx + shx);
                ay += lrelu(bf2f((unsigned short)(p >> 16)) * scy + shy);
            } else {
                float2 w = *(const float2*)((const float*)Zin + (size_t)i0 * DIM + lane * 2);
                ax += w.x; ay += w.y;
            }
        }
    }
    float2 o; o.x = ax; o.y = ay;
    *(float2*)(hz + (size_t)node * DIM + (size_t)lane * 2) = o;
}

// ---------------- fused MLP v4b: 4 weight mats in LDS, 256 rows/block, 4 slabs,
// in-register BN stats, z written as bf16 (half write traffic; stats stay f32).
__device__ __forceinline__ int t1idx(int row, int col) {
    return (row * 128 + col) ^ ((row & 7) << 2);
}

__global__ __launch_bounds__(256) void mlp_mfma(const float* __restrict__ hz,
                                                const unsigned short* __restrict__ W1h,
                                                const unsigned short* __restrict__ W1l,
                                                const float* __restrict__ b1,
                                                const unsigned short* __restrict__ W2h,
                                                const unsigned short* __restrict__ W2l,
                                                const float* __restrict__ b2,
                                                unsigned short* __restrict__ Zb,
                                                float* __restrict__ stats) {
    __shared__ unsigned short wlds[4][16384];  // 128 KB
    __shared__ float t1s[8192];                // 32 KB swizzled
    int tid = threadIdx.x;
    int w = tid >> 6, l = tid & 63;
    int l15 = l & 15, kg = l >> 4;

    float bias1[8], bias2[8];
#pragma unroll
    for (int nt = 0; nt < 8; nt++) {
        bias1[nt] = b1[nt * 16 + l15];
        bias2[nt] = b2[nt * 16 + l15];
    }
    {
        const float4* s0 = (const float4*)W1h;
        const float4* s1 = (const float4*)W1l;
        const float4* s2 = (const float4*)W2h;
        const float4* s3 = (const float4*)W2l;
        float4* d0 = (float4*)wlds[0];
        float4* d1 = (float4*)wlds[1];
        float4* d2 = (float4*)wlds[2];
        float4* d3 = (float4*)wlds[3];
        for (int i = tid; i < 2048; i += 256) {
            d0[i] = s0[i]; d1[i] = s1[i]; d2[i] = s2[i]; d3[i] = s3[i];
        }
    }
    __syncthreads();

    float sacc[8], s2acc[8];
#pragma unroll
    for (int nt = 0; nt < 8; nt++) { sacc[nt] = 0.f; s2acc[nt] = 0.f; }

    int blk0 = blockIdx.x * 256;
    float4 abuf[8];
    {
        int mrow = blk0 + w * 16 + l15;
#pragma unroll
        for (int kb = 0; kb < 4; kb++) {
            if (mrow < NN) {
                abuf[kb * 2]     = *(const float4*)(hz + (size_t)mrow * DIM + kb * 32 + kg * 8);
                abuf[kb * 2 + 1] = *(const float4*)(hz + (size_t)mrow * DIM + kb * 32 + kg * 8 + 4);
            } else {
                abuf[kb * 2] = make_float4(0.f, 0.f, 0.f, 0.f);
                abuf[kb * 2 + 1] = make_float4(0.f, 0.f, 0.f, 0.f);
            }
        }
    }

#pragma unroll
    for (int slab = 0; slab < 4; slab++) {
        bf16x8 ah[4], al[4];
#pragma unroll
        for (int kb = 0; kb < 4; kb++) split8v(abuf[kb * 2], abuf[kb * 2 + 1], ah[kb], al[kb]);
        if (slab < 3) {
            int mrow = blk0 + (slab + 1) * 64 + w * 16 + l15;
#pragma unroll
            for (int kb = 0; kb < 4; kb++) {
                if (mrow < NN) {
                    abuf[kb * 2]     = *(const float4*)(hz + (size_t)mrow * DIM + kb * 32 + kg * 8);
                    abuf[kb * 2 + 1] = *(const float4*)(hz + (size_t)mrow * DIM + kb * 32 + kg * 8 + 4);
                } else {
                    abuf[kb * 2] = make_float4(0.f, 0.f, 0.f, 0.f);
                    abuf[kb * 2 + 1] = make_float4(0.f, 0.f, 0.f, 0.f);
                }
            }
        }
#pragma unroll
        for (int nt = 0; nt < 8; nt++) {
            f32x4 a0 = {0.f, 0.f, 0.f, 0.f}, a1 = a0, a2 = a0;
#pragma unroll
            for (int kb = 0; kb < 4; kb++) {
                int off = nt * 2048 + kb * 512 + l * 8;
                bf16x8 wh = *(const bf16x8*)(&wlds[0][off]);
                bf16x8 wl = *(const bf16x8*)(&wlds[1][off]);
                a0 = __builtin_amdgcn_mfma_f32_16x16x32_bf16(ah[kb], wh, a0, 0, 0, 0);
                a1 = __builtin_amdgcn_mfma_f32_16x16x32_bf16(ah[kb], wl, a1, 0, 0, 0);
                a2 = __builtin_amdgcn_mfma_f32_16x16x32_bf16(al[kb], wh, a2, 0, 0, 0);
            }
            int colw = nt * 16 + l15;
#pragma unroll
            for (int j = 0; j < 4; j++) {
                t1s[t1idx(w * 16 + kg * 4 + j, colw)] = lrelu(a0[j] + a1[j] + a2[j] + bias1[nt]);
            }
        }
        bf16x8 a2h[4], a2l[4];
#pragma unroll
        for (int kb = 0; kb < 4; kb++) {
            int c = kb * 32 + kg * 8;
            float4 q0 = *(const float4*)(&t1s[t1idx(w * 16 + l15, c)]);
            float4 q1 = *(const float4*)(&t1s[t1idx(w * 16 + l15, c + 4)]);
            split8v(q0, q1, a2h[kb], a2l[kb]);
        }
#pragma unroll
        for (int nt = 0; nt < 8; nt++) {
            f32x4 a0 = {0.f, 0.f, 0.f, 0.f}, a1 = a0, a2 = a0;
#pragma unroll
            for (int kb = 0; kb < 4; kb++) {
                int off = nt * 2048 + kb * 512 + l * 8;
                bf16x8 wh = *(const bf16x8*)(&wlds[2][off]);
                bf16x8 wl = *(const bf16x8*)(&wlds[3][off]);
                a0 = __builtin_amdgcn_mfma_f32_16x16x32_bf16(a2h[kb], wh, a0, 0, 0, 0);
                a1 = __builtin_amdgcn_mfma_f32_16x16x32_bf16(a2h[kb], wl, a1, 0, 0, 0);
                a2 = __builtin_amdgcn_mfma_f32_16x16x32_bf16(a2l[kb], wh, a2, 0, 0, 0);
            }
#pragma unroll
            for (int j = 0; j < 4; j++) {
                int r = blk0 + slab * 64 + w * 16 + kg * 4 + j;
                if (r < NN) {
                    float o = a0[j] + a1[j] + a2[j] + bias2[nt];
                    Zb[(size_t)r * DIM + nt * 16 + l15] = f2bf(o);
                    sacc[nt] += o;
                    s2acc[nt] += o * o;
                }
            }
        }
    }

    __syncthreads();
    int part = w * 4 + kg;
#pragma unroll
    for (int nt = 0; nt < 8; nt++) {
        t1s[part * 128 + nt * 16 + l15] = sacc[nt];
        t1s[2048 + part * 128 + nt * 16 + l15] = s2acc[nt];
    }
    __syncthreads();
    if (tid < DIM) {
        float ts = 0.f, ts2 = 0.f;
#pragma unroll
        for (int p = 0; p < 16; p++) {
            ts += t1s[p * 128 + tid];
            ts2 += t1s[2048 + p * 128 + tid];
        }
        atomicAdd(&stats[tid], ts);
        atomicAdd(&stats[DIM + tid], ts2);
    }
}

// ---------------- gumbel softmax per node with inline BN finalize (bf16 z input)
__global__ __launch_bounds__(256) void softmaxc_kernel(const unsigned short* __restrict__ Zb,
                                                       const float* __restrict__ stats,
                                                       const float* __restrict__ gamma,
                                                       const float* __restrict__ beta,
                                                       const float* __restrict__ G,
                                                       float* __restrict__ C) {
    int node = blockIdx.x * 4 + (threadIdx.x >> 6);
    if (node >= NN) return;
    int lane = threadIdx.x & 63;
    int c0 = lane * 2, c1 = lane * 2 + 1;
    float mu0 = stats[c0] * (1.f / NN);
    float mu1 = stats[c1] * (1.f / NN);
    float var0 = stats[DIM + c0] * (1.f / NN) - mu0 * mu0;
    float var1 = stats[DIM + c1] * (1.f / NN) - mu1 * mu1;
    float scx = gamma[c0] * rsqrtf(var0 + BN_EPS);
    float scy = gamma[c1] * rsqrtf(var1 + BN_EPS);
    float shx = beta[c0] - mu0 * scx;
    float shy = beta[c1] - mu1 * scy;
    unsigned p = ((const unsigned*)(Zb + (size_t)node * DIM))[lane];
    float2 gv = *(const float2*)(G + (size_t)node * DIM + lane * 2);
    float vx = bf2f((unsigned short)p) * scx + shx + gv.x;
    float vy = bf2f((unsigned short)(p >> 16)) * scy + shy + gv.y;
    float m = fmaxf(vx, vy);
#pragma unroll
    for (int o = 32; o >= 1; o >>= 1) m = fmaxf(m, __shfl_xor(m, o));
    float ex = __expf(vx - m), ey = __expf(vy - m);
    float s = ex + ey;
#pragma unroll
    for (int o = 32; o >= 1; o >>= 1) s += __shfl_xor(s, o);
    float inv = 1.f / s;
    float2 c;
    c.x = ex * inv;
    c.y = ey * inv;
    *(float2*)(C + (size_t)node * DIM + lane * 2) = c;
}

// ---------------- pool v2: block per row-chunk; batch sorted -> flush on graph change
#define POOL_BLOCKS 512
__global__ __launch_bounds__(128) void pool_kernel(const float* __restrict__ C,
                                                   const int* __restrict__ batch,
                                                   float* __restrict__ pooled) {
    int col = threadIdx.x;
    int rpb = (NN + POOL_BLOCKS - 1) / POOL_BLOCKS;
    int r0 = blockIdx.x * rpb;
    int r1 = min(NN, r0 + rpb);
    if (r0 >= NN) return;
    int curg = batch[r0];
    float acc = 0.f;
    for (int r = r0; r < r1; r++) {
        int g = batch[r];
        if (g != curg) {
            atomicAdd(&pooled[curg * DIM + col], acc);
            acc = 0.f;
            curg = g;
        }
        acc += C[(size_t)r * DIM + col];
    }
    atomicAdd(&pooled[curg * DIM + col], acc);
}

// ---------------- dense head
__global__ __launch_bounds__(128) void head_kernel(const float* __restrict__ pooled,
                                                   const float* __restrict__ Wd1,
                                                   const float* __restrict__ bd1,
                                                   const float* __restrict__ Wd2,
                                                   const float* __restrict__ bd2,
                                                   float* __restrict__ out) {
    int g = blockIdx.x;
    int j = threadIdx.x;
    __shared__ float hid[DIM];
    __shared__ float logits[NCLASSES];
    float acc = bd1[j];
    for (int k = 0; k < DIM; k++) acc += pooled[g * DIM + k] * Wd1[k * DIM + j];
    hid[j] = lrelu(acc);
    __syncthreads();
    if (j < NCLASSES) {
        float a = bd2[j];
        for (int k = 0; k < DIM; k++) a += hid[k] * Wd2[k * NCLASSES + j];
        logits[j] = a;
    }
    __syncthreads();
    if (j == 0) {
        float m = -1e30f;
        for (int c = 0; c < NCLASSES; c++) m = fmaxf(m, logits[c]);
        float s = 0.f, e[NCLASSES];
        for (int c = 0; c < NCLASSES; c++) { e[c] = __expf(logits[c] - m); s += e[c]; }
        float inv = 1.f / s;
        for (int c = 0; c < NCLASSES; c++) out[g * NCLASSES + c] = e[c] * inv;
    }
}

extern "C" void kernel_launch(void* const* d_in, const int* in_sizes, int n_in,
                              void* d_out, int out_size, void* d_ws, size_t ws_size,
                              hipStream_t stream) {
    const float* x = (const float*)d_in[0];
    const int* edges = (const int*)d_in[1];
    const int* batch = (const int*)d_in[2];
    const float* gum = (const float*)d_in[3];
    const float* W1s = (const float*)d_in[4];
    const float* b1s = (const float*)d_in[5];
    const float* W2s = (const float*)d_in[6];
    const float* b2s = (const float*)d_in[7];
    const float* gammas = (const float*)d_in[8];
    const float* betas = (const float*)d_in[9];
    const float* Wd1 = (const float*)d_in[10];
    const float* bd1 = (const float*)d_in[11];
    const float* Wd2 = (const float*)d_in[12];
    const float* bd2 = (const float*)d_in[13];

    float* out = (float*)d_out;
    float* cout = out + NGRAPHS * NCLASSES;

    const size_t ND = (size_t)NN * DIM;
    unsigned short* zb = (unsigned short*)d_ws;      // ND bf16 (pre-BN layer output)
    float* hz = (float*)(zb + ND);                   // ND f32 (gather out / MLP in)
    unsigned short* Wh = (unsigned short*)(hz + ND); // 16*16384 bf16 (frag-major hi)
    unsigned short* Wl = Wh + 16 * 16384;            // 16*16384 bf16 (frag-major lo)
    float* stats8 = (float*)(Wl + 16 * 16384);       // 8 * 2*DIM
    float* pooled = stats8 + NLAYERS * 2 * DIM;      // NGRAPHS*DIM
    int* counts = (int*)(pooled + NGRAPHS * DIM);    // NN
    int* offsets = counts + NN;                      // NN+1
    int* cursor = offsets + NN + 1;                  // NN
    int* csr_src = cursor + NN;                      // NE
    int* psums = csr_src + NE;                       // SCAN_BLOCKS

    const int MLP_BLOCKS = (NN + 255) / 256;
    const int EDGE_BLOCKS = (NE + 255) / 256;
    const int NODE_BLOCKS = (NN + 3) / 4;

    // ---- CSR build + weight prep (static per launch)
    hipMemsetAsync(counts, 0, NN * sizeof(int), stream);
    degree_kernel<<<EDGE_BLOCKS, 256, 0, stream>>>(edges, counts);
    psum_kernel<<<SCAN_BLOCKS, 256, 0, stream>>>(counts, psums);
    pscan_kernel<<<1, 256, 0, stream>>>(psums);
    owrite_kernel<<<SCAN_BLOCKS, 256, 0, stream>>>(counts, psums, offsets);
    hipMemcpyAsync(cursor, offsets, NN * sizeof(int), hipMemcpyDeviceToDevice, stream);
    fill_kernel<<<EDGE_BLOCKS, 256, 0, stream>>>(edges, cursor, csr_src);
    wprep_kernel<<<(16 * 16384 + 255) / 256, 256, 0, stream>>>(W1s, W2s, Wh, Wl);

    hipMemsetAsync(stats8, 0, NLAYERS * 2 * DIM * sizeof(float), stream);

    for (int i = 0; i < NLAYERS; i++) {
        const unsigned short* W1h = Wh + (size_t)(2 * i) * 16384;
        const unsigned short* W1l = Wl + (size_t)(2 * i) * 16384;
        const unsigned short* W2h = Wh + (size_t)(2 * i + 1) * 16384;
        const unsigned short* W2l = Wl + (size_t)(2 * i + 1) * 16384;
        const float* b1 = b1s + (size_t)i * DIM;
        const float* b2 = b2s + (size_t)i * DIM;
        float* stats = stats8 + (size_t)i * 2 * DIM;

        if (i == 0)
            gather_kernel<0><<<NODE_BLOCKS, 256, 0, stream>>>(x, nullptr, nullptr, nullptr,
                                                              offsets, csr_src, hz);
        else
            gather_kernel<1><<<NODE_BLOCKS, 256, 0, stream>>>(
                zb, stats8 + (size_t)(i - 1) * 2 * DIM, gammas + (size_t)(i - 1) * DIM,
                betas + (size_t)(i - 1) * DIM, offsets, csr_src, hz);
        mlp_mfma<<<MLP_BLOCKS, 256, 0, stream>>>(hz, W1h, W1l, b1, W2h, W2l, b2, zb, stats);
    }

    hipMemsetAsync(pooled, 0, NGRAPHS * DIM * sizeof(float), stream);
    softmaxc_kernel<<<NODE_BLOCKS, 256, 0, stream>>>(
        zb, stats8 + (size_t)(NLAYERS - 1) * 2 * DIM, gammas + (size_t)(NLAYERS - 1) * DIM,
        betas + (size_t)(NLAYERS - 1) * DIM, gum, cout);
    pool_kernel<<<POOL_BLOCKS, 128, 0, stream>>>(cout, batch, pooled);
    head_kernel<<<NGRAPHS, 128, 0, stream>>>(pooled, Wd1, bd1, Wd2, bd2, out);
}

// Round 16
// 632.623 us; speedup vs baseline: 2.0614x; 1.0388x over previous
//
#include <hip/hip_runtime.h>

#define NN 50000
#define NE 600000
#define DIM 128
#define NLAYERS 8
#define NCLASSES 10
#define NGRAPHS 64
#define BN_EPS 1e-5f
#define SLOPE 0.01f

typedef __attribute__((ext_vector_type(8))) short bf16x8;
typedef __attribute__((ext_vector_type(4))) float f32x4;

__device__ __forceinline__ float lrelu(float v) { return v > 0.f ? v : SLOPE * v; }

__device__ __forceinline__ unsigned short f2bf(float x) {
    unsigned u = __builtin_bit_cast(unsigned, x);
    unsigned r = (u + 0x7FFFu + ((u >> 16) & 1u)) >> 16;
    return (unsigned short)r;
}
__device__ __forceinline__ float bf2f(unsigned short h) {
    return __builtin_bit_cast(float, (unsigned)h << 16);
}
// split 8 floats (two float4) into hi+lo bf16x8
__device__ __forceinline__ void split8v(float4 q0, float4 q1, bf16x8& hi, bf16x8& lo) {
    float buf[8] = {q0.x, q0.y, q0.z, q0.w, q1.x, q1.y, q1.z, q1.w};
#pragma unroll
    for (int j = 0; j < 8; j++) {
        float x = buf[j];
        unsigned short h = f2bf(x);
        hi[j] = (short)h;
        lo[j] = (short)f2bf(x - bf2f(h));
    }
}

// ---------------- CSR build: degree histogram
__global__ __launch_bounds__(256) void degree_kernel(const int* __restrict__ edges,
                                                     int* __restrict__ counts) {
    int e = blockIdx.x * 256 + threadIdx.x;
    if (e >= NE) return;
    atomicAdd(&counts[edges[NE + e]], 1);
}

// ---------------- hierarchical scan
#define SCAN_BLOCKS ((NN + 255) / 256)
__global__ __launch_bounds__(256) void psum_kernel(const int* __restrict__ counts,
                                                   int* __restrict__ psums) {
    __shared__ int red[256];
    int i = blockIdx.x * 256 + threadIdx.x;
    red[threadIdx.x] = (i < NN) ? counts[i] : 0;
    __syncthreads();
    for (int s = 128; s > 0; s >>= 1) {
        if (threadIdx.x < s) red[threadIdx.x] += red[threadIdx.x + s];
        __syncthreads();
    }
    if (threadIdx.x == 0) psums[blockIdx.x] = red[0];
}
__global__ __launch_bounds__(256) void pscan_kernel(int* __restrict__ psums) {
    __shared__ int buf[256];
    int t = threadIdx.x;
    buf[t] = (t < SCAN_BLOCKS) ? psums[t] : 0;
    __syncthreads();
    for (int o = 1; o < 256; o <<= 1) {
        int v = (t >= o) ? buf[t - o] : 0;
        __syncthreads();
        buf[t] += v;
        __syncthreads();
    }
    if (t < SCAN_BLOCKS) psums[t] = (t == 0) ? 0 : buf[t - 1];  // exclusive
}
// writes offsets AND cursor (cursor = exclusive start), deleting the d2d memcpy
__global__ __launch_bounds__(256) void owrite_kernel(const int* __restrict__ counts,
                                                     const int* __restrict__ psums,
                                                     int* __restrict__ offsets,
                                                     int* __restrict__ cursor) {
    int b = blockIdx.x, t = threadIdx.x;
    int i = b * 256 + t;
    __shared__ int buf[256];
    int v = (i < NN) ? counts[i] : 0;
    buf[t] = v;
    __syncthreads();
    for (int o = 1; o < 256; o <<= 1) {
        int u = (t >= o) ? buf[t - o] : 0;
        __syncthreads();
        buf[t] += u;
        __syncthreads();
    }
    if (i < NN) {
        int incl = psums[b] + buf[t];
        offsets[i + 1] = incl;
        cursor[i] = incl - v;
    }
    if (i == 0) offsets[0] = 0;
}

// ---------------- CSR build: fill src lists
__global__ __launch_bounds__(256) void fill_kernel(const int* __restrict__ edges,
                                                   int* __restrict__ cursor,
                                                   int* __restrict__ csr_src) {
    int e = blockIdx.x * 256 + threadIdx.x;
    if (e >= NE) return;
    int d = edges[NE + e];
    int p = atomicAdd(&cursor[d], 1);
    csr_src[p] = edges[e];
}

// ---------------- weight prep: hi/lo bf16 of W^T in FRAGMENT-MAJOR order
__global__ __launch_bounds__(256) void wprep_kernel(const float* __restrict__ W1s,
                                                    const float* __restrict__ W2s,
                                                    unsigned short* __restrict__ Wh,
                                                    unsigned short* __restrict__ Wl) {
    int gid = blockIdx.x * 256 + threadIdx.x;  // 16 * 16384
    if (gid >= 16 * 16384) return;
    int mat = gid >> 14;
    int idx = gid & 16383;
    int nt = idx >> 11, kb = (idx >> 9) & 3, lane = (idx >> 3) & 63, j = idx & 7;
    int l15 = lane & 15, kg = lane >> 4;
    int n = nt * 16 + l15, k = kb * 32 + kg * 8 + j;
    int layer = mat >> 1, which = mat & 1;
    const float* src = which ? (W2s + (size_t)layer * 16384) : (W1s + (size_t)layer * 16384);
    float x = src[k * DIM + n];
    unsigned short h = f2bf(x);
    Wh[gid] = h;
    Wl[gid] = f2bf(x - bf2f(h));
}

// ---------------- gather (+ inline BN finalize + lrelu of producing layer):
// BN=0: Zin = x (f32). BN=1: Zin = zb (bf16 rows).
template <int BN>
__global__ __launch_bounds__(256) void gather_kernel(const void* __restrict__ Zin,
                                                     const float* __restrict__ stats,
                                                     const float* __restrict__ gamma,
                                                     const float* __restrict__ beta,
                                                     const int* __restrict__ offsets,
                                                     const int* __restrict__ csr_src,
                                                     float* __restrict__ hz) {
    int node = blockIdx.x * 4 + (threadIdx.x >> 6);
    if (node >= NN) return;
    int lane = threadIdx.x & 63;
    float scx = 0.f, scy = 0.f, shx = 0.f, shy = 0.f;
    if (BN) {
        int c0 = lane * 2, c1 = lane * 2 + 1;
        float mu0 = stats[c0] * (1.f / NN);
        float mu1 = stats[c1] * (1.f / NN);
        float var0 = stats[DIM + c0] * (1.f / NN) - mu0 * mu0;
        float var1 = stats[DIM + c1] * (1.f / NN) - mu1 * mu1;
        scx = gamma[c0] * rsqrtf(var0 + BN_EPS);
        scy = gamma[c1] * rsqrtf(var1 + BN_EPS);
        shx = beta[c0] - mu0 * scx;
        shy = beta[c1] - mu1 * scy;
    }
    int beg = offsets[node], end = offsets[node + 1];
    float ax, ay;
    if (BN) {
        unsigned p = ((const unsigned*)((const unsigned short*)Zin + (size_t)node * DIM))[lane];
        ax = lrelu(bf2f((unsigned short)p) * scx + shx);
        ay = lrelu(bf2f((unsigned short)(p >> 16)) * scy + shy);
    } else {
        float2 v = *(const float2*)((const float*)Zin + (size_t)node * DIM + lane * 2);
        ax = v.x; ay = v.y;
    }

    for (int base = beg; base < end; base += 64) {
        int cnt = min(64, end - base);
        int myidx = (lane < cnt) ? csr_src[base + lane] : 0;
        int e = 0;
        for (; e + 4 <= cnt; e += 4) {
            int i0 = __shfl(myidx, e);
            int i1 = __shfl(myidx, e + 1);
            int i2 = __shfl(myidx, e + 2);
            int i3 = __shfl(myidx, e + 3);
            if (BN) {
                const unsigned short* zb = (const unsigned short*)Zin;
                unsigned p0 = ((const unsigned*)(zb + (size_t)i0 * DIM))[lane];
                unsigned p1 = ((const unsigned*)(zb + (size_t)i1 * DIM))[lane];
                unsigned p2 = ((const unsigned*)(zb + (size_t)i2 * DIM))[lane];
                unsigned p3 = ((const unsigned*)(zb + (size_t)i3 * DIM))[lane];
                ax += lrelu(bf2f((unsigned short)p0) * scx + shx) +
                      lrelu(bf2f((unsigned short)p1) * scx + shx) +
                      lrelu(bf2f((unsigned short)p2) * scx + shx) +
                      lrelu(bf2f((unsigned short)p3) * scx + shx);
                ay += lrelu(bf2f((unsigned short)(p0 >> 16)) * scy + shy) +
                      lrelu(bf2f((unsigned short)(p1 >> 16)) * scy + shy) +
                      lrelu(bf2f((unsigned short)(p2 >> 16)) * scy + shy) +
                      lrelu(bf2f((unsigned short)(p3 >> 16)) * scy + shy);
            } else {
                const float* zf = (const float*)Zin;
                float2 w0 = *(const float2*)(zf + (size_t)i0 * DIM + lane * 2);
                float2 w1 = *(const float2*)(zf + (size_t)i1 * DIM + lane * 2);
                float2 w2 = *(const float2*)(zf + (size_t)i2 * DIM + lane * 2);
                float2 w3 = *(const float2*)(zf + (size_t)i3 * DIM + lane * 2);
                ax += (w0.x + w1.x) + (w2.x + w3.x);
                ay += (w0.y + w1.y) + (w2.y + w3.y);
            }
        }
        for (; e < cnt; e++) {
            int i0 = __shfl(myidx, e);
            if (BN) {
                unsigned p = ((const unsigned*)((const unsigned short*)Zin + (size_t)i0 * DIM))[lane];
                ax += lrelu(bf2f((unsigned short)p) * scx + shx);
                ay += lrelu(bf2f((unsigned short)(p >> 16)) * scy + shy);
            } else {
                float2 w = *(const float2*)((const float*)Zin + (size_t)i0 * DIM + lane * 2);
                ax += w.x; ay += w.y;
            }
        }
    }
    float2 o; o.x = ax; o.y = ay;
    *(float2*)(hz + (size_t)node * DIM + (size_t)lane * 2) = o;
}

// ---------------- fused MLP v4b: 4 weight mats in LDS, 256 rows/block, 4 slabs,
// in-register BN stats, z written as bf16.
__device__ __forceinline__ int t1idx(int row, int col) {
    return (row * 128 + col) ^ ((row & 7) << 2);
}

__global__ __launch_bounds__(256) void mlp_mfma(const float* __restrict__ hz,
                                                const unsigned short* __restrict__ W1h,
                                                const unsigned short* __restrict__ W1l,
                                                const float* __restrict__ b1,
                                                const unsigned short* __restrict__ W2h,
                                                const unsigned short* __restrict__ W2l,
                                                const float* __restrict__ b2,
                                                unsigned short* __restrict__ Zb,
                                                float* __restrict__ stats) {
    __shared__ unsigned short wlds[4][16384];  // 128 KB
    __shared__ float t1s[8192];                // 32 KB swizzled
    int tid = threadIdx.x;
    int w = tid >> 6, l = tid & 63;
    int l15 = l & 15, kg = l >> 4;

    float bias1[8], bias2[8];
#pragma unroll
    for (int nt = 0; nt < 8; nt++) {
        bias1[nt] = b1[nt * 16 + l15];
        bias2[nt] = b2[nt * 16 + l15];
    }
    {
        const float4* s0 = (const float4*)W1h;
        const float4* s1 = (const float4*)W1l;
        const float4* s2 = (const float4*)W2h;
        const float4* s3 = (const float4*)W2l;
        float4* d0 = (float4*)wlds[0];
        float4* d1 = (float4*)wlds[1];
        float4* d2 = (float4*)wlds[2];
        float4* d3 = (float4*)wlds[3];
        for (int i = tid; i < 2048; i += 256) {
            d0[i] = s0[i]; d1[i] = s1[i]; d2[i] = s2[i]; d3[i] = s3[i];
        }
    }
    __syncthreads();

    float sacc[8], s2acc[8];
#pragma unroll
    for (int nt = 0; nt < 8; nt++) { sacc[nt] = 0.f; s2acc[nt] = 0.f; }

    int blk0 = blockIdx.x * 256;
    float4 abuf[8];
    {
        int mrow = blk0 + w * 16 + l15;
#pragma unroll
        for (int kb = 0; kb < 4; kb++) {
            if (mrow < NN) {
                abuf[kb * 2]     = *(const float4*)(hz + (size_t)mrow * DIM + kb * 32 + kg * 8);
                abuf[kb * 2 + 1] = *(const float4*)(hz + (size_t)mrow * DIM + kb * 32 + kg * 8 + 4);
            } else {
                abuf[kb * 2] = make_float4(0.f, 0.f, 0.f, 0.f);
                abuf[kb * 2 + 1] = make_float4(0.f, 0.f, 0.f, 0.f);
            }
        }
    }

#pragma unroll
    for (int slab = 0; slab < 4; slab++) {
        bf16x8 ah[4], al[4];
#pragma unroll
        for (int kb = 0; kb < 4; kb++) split8v(abuf[kb * 2], abuf[kb * 2 + 1], ah[kb], al[kb]);
        if (slab < 3) {
            int mrow = blk0 + (slab + 1) * 64 + w * 16 + l15;
#pragma unroll
            for (int kb = 0; kb < 4; kb++) {
                if (mrow < NN) {
                    abuf[kb * 2]     = *(const float4*)(hz + (size_t)mrow * DIM + kb * 32 + kg * 8);
                    abuf[kb * 2 + 1] = *(const float4*)(hz + (size_t)mrow * DIM + kb * 32 + kg * 8 + 4);
                } else {
                    abuf[kb * 2] = make_float4(0.f, 0.f, 0.f, 0.f);
                    abuf[kb * 2 + 1] = make_float4(0.f, 0.f, 0.f, 0.f);
                }
            }
        }
#pragma unroll
        for (int nt = 0; nt < 8; nt++) {
            f32x4 a0 = {0.f, 0.f, 0.f, 0.f}, a1 = a0, a2 = a0;
#pragma unroll
            for (int kb = 0; kb < 4; kb++) {
                int off = nt * 2048 + kb * 512 + l * 8;
                bf16x8 wh = *(const bf16x8*)(&wlds[0][off]);
                bf16x8 wl = *(const bf16x8*)(&wlds[1][off]);
                a0 = __builtin_amdgcn_mfma_f32_16x16x32_bf16(ah[kb], wh, a0, 0, 0, 0);
                a1 = __builtin_amdgcn_mfma_f32_16x16x32_bf16(ah[kb], wl, a1, 0, 0, 0);
                a2 = __builtin_amdgcn_mfma_f32_16x16x32_bf16(al[kb], wh, a2, 0, 0, 0);
            }
            int colw = nt * 16 + l15;
#pragma unroll
            for (int j = 0; j < 4; j++) {
                t1s[t1idx(w * 16 + kg * 4 + j, colw)] = lrelu(a0[j] + a1[j] + a2[j] + bias1[nt]);
            }
        }
        bf16x8 a2h[4], a2l[4];
#pragma unroll
        for (int kb = 0; kb < 4; kb++) {
            int c = kb * 32 + kg * 8;
            float4 q0 = *(const float4*)(&t1s[t1idx(w * 16 + l15, c)]);
            float4 q1 = *(const float4*)(&t1s[t1idx(w * 16 + l15, c + 4)]);
            split8v(q0, q1, a2h[kb], a2l[kb]);
        }
#pragma unroll
        for (int nt = 0; nt < 8; nt++) {
            f32x4 a0 = {0.f, 0.f, 0.f, 0.f}, a1 = a0, a2 = a0;
#pragma unroll
            for (int kb = 0; kb < 4; kb++) {
                int off = nt * 2048 + kb * 512 + l * 8;
                bf16x8 wh = *(const bf16x8*)(&wlds[2][off]);
                bf16x8 wl = *(const bf16x8*)(&wlds[3][off]);
                a0 = __builtin_amdgcn_mfma_f32_16x16x32_bf16(a2h[kb], wh, a0, 0, 0, 0);
                a1 = __builtin_amdgcn_mfma_f32_16x16x32_bf16(a2h[kb], wl, a1, 0, 0, 0);
                a2 = __builtin_amdgcn_mfma_f32_16x16x32_bf16(a2l[kb], wh, a2, 0, 0, 0);
            }
#pragma unroll
            for (int j = 0; j < 4; j++) {
                int r = blk0 + slab * 64 + w * 16 + kg * 4 + j;
                if (r < NN) {
                    float o = a0[j] + a1[j] + a2[j] + bias2[nt];
                    Zb[(size_t)r * DIM + nt * 16 + l15] = f2bf(o);
                    sacc[nt] += o;
                    s2acc[nt] += o * o;
                }
            }
        }
    }

    __syncthreads();
    int part = w * 4 + kg;
#pragma unroll
    for (int nt = 0; nt < 8; nt++) {
        t1s[part * 128 + nt * 16 + l15] = sacc[nt];
        t1s[2048 + part * 128 + nt * 16 + l15] = s2acc[nt];
    }
    __syncthreads();
    if (tid < DIM) {
        float ts = 0.f, ts2 = 0.f;
#pragma unroll
        for (int p = 0; p < 16; p++) {
            ts += t1s[p * 128 + tid];
            ts2 += t1s[2048 + p * 128 + tid];
        }
        atomicAdd(&stats[tid], ts);
        atomicAdd(&stats[DIM + tid], ts2);
    }
}

// ---------------- fused gumbel softmax + pool: 4 waves x 16 nodes/wave;
// per-wave register column-partials, flushed on graph boundary (batch sorted).
__global__ __launch_bounds__(256) void softpool_kernel(const unsigned short* __restrict__ Zb,
                                                       const float* __restrict__ stats,
                                                       const float* __restrict__ gamma,
                                                       const float* __restrict__ beta,
                                                       const float* __restrict__ G,
                                                       const int* __restrict__ batch,
                                                       float* __restrict__ C,
                                                       float* __restrict__ pooled) {
    int wv = threadIdx.x >> 6;
    int lane = threadIdx.x & 63;
    int n0 = blockIdx.x * 64 + wv * 16;
    if (n0 >= NN) return;
    int n1 = min(NN, n0 + 16);
    int c0 = lane * 2, c1 = lane * 2 + 1;
    float mu0 = stats[c0] * (1.f / NN);
    float mu1 = stats[c1] * (1.f / NN);
    float var0 = stats[DIM + c0] * (1.f / NN) - mu0 * mu0;
    float var1 = stats[DIM + c1] * (1.f / NN) - mu1 * mu1;
    float scx = gamma[c0] * rsqrtf(var0 + BN_EPS);
    float scy = gamma[c1] * rsqrtf(var1 + BN_EPS);
    float shx = beta[c0] - mu0 * scx;
    float shy = beta[c1] - mu1 * scy;

    int curg = batch[n0];
    float px = 0.f, py = 0.f;
    for (int node = n0; node < n1; node++) {
        int g = batch[node];
        if (g != curg) {
            atomicAdd(&pooled[curg * DIM + c0], px);
            atomicAdd(&pooled[curg * DIM + c1], py);
            px = 0.f; py = 0.f;
            curg = g;
        }
        unsigned p = ((const unsigned*)(Zb + (size_t)node * DIM))[lane];
        float2 gv = *(const float2*)(G + (size_t)node * DIM + lane * 2);
        float vx = bf2f((unsigned short)p) * scx + shx + gv.x;
        float vy = bf2f((unsigned short)(p >> 16)) * scy + shy + gv.y;
        float m = fmaxf(vx, vy);
#pragma unroll
        for (int o = 32; o >= 1; o >>= 1) m = fmaxf(m, __shfl_xor(m, o));
        float ex = __expf(vx - m), ey = __expf(vy - m);
        float s = ex + ey;
#pragma unroll
        for (int o = 32; o >= 1; o >>= 1) s += __shfl_xor(s, o);
        float inv = 1.f / s;
        float cx = ex * inv, cy = ey * inv;
        float2 c; c.x = cx; c.y = cy;
        *(float2*)(C + (size_t)node * DIM + lane * 2) = c;
        px += cx; py += cy;
    }
    atomicAdd(&pooled[curg * DIM + c0], px);
    atomicAdd(&pooled[curg * DIM + c1], py);
}

// ---------------- dense head
__global__ __launch_bounds__(128) void head_kernel(const float* __restrict__ pooled,
                                                   const float* __restrict__ Wd1,
                                                   const float* __restrict__ bd1,
                                                   const float* __restrict__ Wd2,
                                                   const float* __restrict__ bd2,
                                                   float* __restrict__ out) {
    int g = blockIdx.x;
    int j = threadIdx.x;
    __shared__ float hid[DIM];
    __shared__ float logits[NCLASSES];
    float acc = bd1[j];
    for (int k = 0; k < DIM; k++) acc += pooled[g * DIM + k] * Wd1[k * DIM + j];
    hid[j] = lrelu(acc);
    __syncthreads();
    if (j < NCLASSES) {
        float a = bd2[j];
        for (int k = 0; k < DIM; k++) a += hid[k] * Wd2[k * NCLASSES + j];
        logits[j] = a;
    }
    __syncthreads();
    if (j == 0) {
        float m = -1e30f;
        for (int c = 0; c < NCLASSES; c++) m = fmaxf(m, logits[c]);
        float s = 0.f, e[NCLASSES];
        for (int c = 0; c < NCLASSES; c++) { e[c] = __expf(logits[c] - m); s += e[c]; }
        float inv = 1.f / s;
        for (int c = 0; c < NCLASSES; c++) out[g * NCLASSES + c] = e[c] * inv;
    }
}

extern "C" void kernel_launch(void* const* d_in, const int* in_sizes, int n_in,
                              void* d_out, int out_size, void* d_ws, size_t ws_size,
                              hipStream_t stream) {
    const float* x = (const float*)d_in[0];
    const int* edges = (const int*)d_in[1];
    const int* batch = (const int*)d_in[2];
    const float* gum = (const float*)d_in[3];
    const float* W1s = (const float*)d_in[4];
    const float* b1s = (const float*)d_in[5];
    const float* W2s = (const float*)d_in[6];
    const float* b2s = (const float*)d_in[7];
    const float* gammas = (const float*)d_in[8];
    const float* betas = (const float*)d_in[9];
    const float* Wd1 = (const float*)d_in[10];
    const float* bd1 = (const float*)d_in[11];
    const float* Wd2 = (const float*)d_in[12];
    const float* bd2 = (const float*)d_in[13];

    float* out = (float*)d_out;
    float* cout = out + NGRAPHS * NCLASSES;

    const size_t ND = (size_t)NN * DIM;
    unsigned short* zb = (unsigned short*)d_ws;      // ND bf16 (pre-BN layer output)
    float* hz = (float*)(zb + ND);                   // ND f32 (gather out / MLP in)
    unsigned short* Wh = (unsigned short*)(hz + ND); // 16*16384 bf16 (frag-major hi)
    unsigned short* Wl = Wh + 16 * 16384;            // 16*16384 bf16 (frag-major lo)
    float* stats8 = (float*)(Wl + 16 * 16384);       // 8 * 2*DIM
    float* pooled = stats8 + NLAYERS * 2 * DIM;      // NGRAPHS*DIM
    int* counts = (int*)(pooled + NGRAPHS * DIM);    // NN
    int* offsets = counts + NN;                      // NN+1
    int* cursor = offsets + NN + 1;                  // NN
    int* csr_src = cursor + NN;                      // NE
    int* psums = csr_src + NE;                       // SCAN_BLOCKS

    const int MLP_BLOCKS = (NN + 255) / 256;
    const int EDGE_BLOCKS = (NE + 255) / 256;
    const int NODE_BLOCKS = (NN + 3) / 4;
    const int SP_BLOCKS = (NN + 63) / 64;

    // ---- CSR build + weight prep (static per launch)
    hipMemsetAsync(counts, 0, NN * sizeof(int), stream);
    degree_kernel<<<EDGE_BLOCKS, 256, 0, stream>>>(edges, counts);
    psum_kernel<<<SCAN_BLOCKS, 256, 0, stream>>>(counts, psums);
    pscan_kernel<<<1, 256, 0, stream>>>(psums);
    owrite_kernel<<<SCAN_BLOCKS, 256, 0, stream>>>(counts, psums, offsets, cursor);
    fill_kernel<<<EDGE_BLOCKS, 256, 0, stream>>>(edges, cursor, csr_src);
    wprep_kernel<<<(16 * 16384 + 255) / 256, 256, 0, stream>>>(W1s, W2s, Wh, Wl);

    hipMemsetAsync(stats8, 0, NLAYERS * 2 * DIM * sizeof(float), stream);

    for (int i = 0; i < NLAYERS; i++) {
        const unsigned short* W1h = Wh + (size_t)(2 * i) * 16384;
        const unsigned short* W1l = Wl + (size_t)(2 * i) * 16384;
        const unsigned short* W2h = Wh + (size_t)(2 * i + 1) * 16384;
        const unsigned short* W2l = Wl + (size_t)(2 * i + 1) * 16384;
        const float* b1 = b1s + (size_t)i * DIM;
        const float* b2 = b2s + (size_t)i * DIM;
        float* stats = stats8 + (size_t)i * 2 * DIM;

        if (i == 0)
            gather_kernel<0><<<NODE_BLOCKS, 256, 0, stream>>>(x, nullptr, nullptr, nullptr,
                                                              offsets, csr_src, hz);
        else
            gather_kernel<1><<<NODE_BLOCKS, 256, 0, stream>>>(
                zb, stats8 + (size_t)(i - 1) * 2 * DIM, gammas + (size_t)(i - 1) * DIM,
                betas + (size_t)(i - 1) * DIM, offsets, csr_src, hz);
        mlp_mfma<<<MLP_BLOCKS, 256, 0, stream>>>(hz, W1h, W1l, b1, W2h, W2l, b2, zb, stats);
    }

    hipMemsetAsync(pooled, 0, NGRAPHS * DIM * sizeof(float), stream);
    softpool_kernel<<<SP_BLOCKS, 256, 0, stream>>>(
        zb, stats8 + (size_t)(NLAYERS - 1) * 2 * DIM, gammas + (size_t)(NLAYERS - 1) * DIM,
        betas + (size_t)(NLAYERS - 1) * DIM, gum, batch, cout, pooled);
    head_kernel<<<NGRAPHS, 128, 0, stream>>>(pooled, Wd1, bd1, Wd2, bd2, out);
}

// Round 17
// 610.819 us; speedup vs baseline: 2.1350x; 1.0357x over previous
//
#include <hip/hip_runtime.h>
#include <hip/hip_bf16.h>

#define NN 50000
#define NE 600000
#define DIM 128
#define NLAYERS 8
#define NCLASSES 10
#define NGRAPHS 64
#define BN_EPS 1e-5f
#define SLOPE 0.01f

typedef __attribute__((ext_vector_type(8))) short bf16x8;
typedef __attribute__((ext_vector_type(4))) float f32x4;

__device__ __forceinline__ float lrelu(float v) { return v > 0.f ? v : SLOPE * v; }

__device__ __forceinline__ unsigned short f2bf(float x) {
    unsigned u = __builtin_bit_cast(unsigned, x);
    unsigned r = (u + 0x7FFFu + ((u >> 16) & 1u)) >> 16;
    return (unsigned short)r;
}
__device__ __forceinline__ float bf2f(unsigned short h) {
    return __builtin_bit_cast(float, (unsigned)h << 16);
}
// split 8 floats into hi+lo bf16x8 via compiler bf16 casts (v_cvt_pk path).
// hi rounding mode is immaterial: lo captures the exact residual x - hi.
__device__ __forceinline__ void split8v(float4 q0, float4 q1, bf16x8& hi, bf16x8& lo) {
    float buf[8] = {q0.x, q0.y, q0.z, q0.w, q1.x, q1.y, q1.z, q1.w};
#pragma unroll
    for (int j = 0; j < 8; j++) {
        float x = buf[j];
        __hip_bfloat16 h = __float2bfloat16(x);
        hi[j] = (short)__builtin_bit_cast(unsigned short, h);
        float r = x - __bfloat162float(h);
        lo[j] = (short)__builtin_bit_cast(unsigned short, __float2bfloat16(r));
    }
}

// ---------------- CSR build: degree histogram
__global__ __launch_bounds__(256) void degree_kernel(const int* __restrict__ edges,
                                                     int* __restrict__ counts) {
    int e = blockIdx.x * 256 + threadIdx.x;
    if (e >= NE) return;
    atomicAdd(&counts[edges[NE + e]], 1);
}

// ---------------- hierarchical scan
#define SCAN_BLOCKS ((NN + 255) / 256)
__global__ __launch_bounds__(256) void psum_kernel(const int* __restrict__ counts,
                                                   int* __restrict__ psums) {
    __shared__ int red[256];
    int i = blockIdx.x * 256 + threadIdx.x;
    red[threadIdx.x] = (i < NN) ? counts[i] : 0;
    __syncthreads();
    for (int s = 128; s > 0; s >>= 1) {
        if (threadIdx.x < s) red[threadIdx.x] += red[threadIdx.x + s];
        __syncthreads();
    }
    if (threadIdx.x == 0) psums[blockIdx.x] = red[0];
}
__global__ __launch_bounds__(256) void pscan_kernel(int* __restrict__ psums) {
    __shared__ int buf[256];
    int t = threadIdx.x;
    buf[t] = (t < SCAN_BLOCKS) ? psums[t] : 0;
    __syncthreads();
    for (int o = 1; o < 256; o <<= 1) {
        int v = (t >= o) ? buf[t - o] : 0;
        __syncthreads();
        buf[t] += v;
        __syncthreads();
    }
    if (t < SCAN_BLOCKS) psums[t] = (t == 0) ? 0 : buf[t - 1];  // exclusive
}
__global__ __launch_bounds__(256) void owrite_kernel(const int* __restrict__ counts,
                                                     const int* __restrict__ psums,
                                                     int* __restrict__ offsets,
                                                     int* __restrict__ cursor) {
    int b = blockIdx.x, t = threadIdx.x;
    int i = b * 256 + t;
    __shared__ int buf[256];
    int v = (i < NN) ? counts[i] : 0;
    buf[t] = v;
    __syncthreads();
    for (int o = 1; o < 256; o <<= 1) {
        int u = (t >= o) ? buf[t - o] : 0;
        __syncthreads();
        buf[t] += u;
        __syncthreads();
    }
    if (i < NN) {
        int incl = psums[b] + buf[t];
        offsets[i + 1] = incl;
        cursor[i] = incl - v;
    }
    if (i == 0) offsets[0] = 0;
}

// ---------------- CSR build: fill src lists
__global__ __launch_bounds__(256) void fill_kernel(const int* __restrict__ edges,
                                                   int* __restrict__ cursor,
                                                   int* __restrict__ csr_src) {
    int e = blockIdx.x * 256 + threadIdx.x;
    if (e >= NE) return;
    int d = edges[NE + e];
    int p = atomicAdd(&cursor[d], 1);
    csr_src[p] = edges[e];
}

// ---------------- weight prep: hi/lo bf16 of W^T in FRAGMENT-MAJOR order
__global__ __launch_bounds__(256) void wprep_kernel(const float* __restrict__ W1s,
                                                    const float* __restrict__ W2s,
                                                    unsigned short* __restrict__ Wh,
                                                    unsigned short* __restrict__ Wl) {
    int gid = blockIdx.x * 256 + threadIdx.x;  // 16 * 16384
    if (gid >= 16 * 16384) return;
    int mat = gid >> 14;
    int idx = gid & 16383;
    int nt = idx >> 11, kb = (idx >> 9) & 3, lane = (idx >> 3) & 63, j = idx & 7;
    int l15 = lane & 15, kg = lane >> 4;
    int n = nt * 16 + l15, k = kb * 32 + kg * 8 + j;
    int layer = mat >> 1, which = mat & 1;
    const float* src = which ? (W2s + (size_t)layer * 16384) : (W1s + (size_t)layer * 16384);
    float x = src[k * DIM + n];
    unsigned short h = f2bf(x);
    Wh[gid] = h;
    Wl[gid] = f2bf(x - bf2f(h));
}

// ---------------- gather (+ inline BN finalize + lrelu of producing layer):
// BN=0: Zin = x (f32). BN=1: Zin = zb (bf16 rows).
template <int BN>
__global__ __launch_bounds__(256) void gather_kernel(const void* __restrict__ Zin,
                                                     const float* __restrict__ stats,
                                                     const float* __restrict__ gamma,
                                                     const float* __restrict__ beta,
                                                     const int* __restrict__ offsets,
                                                     const int* __restrict__ csr_src,
                                                     float* __restrict__ hz) {
    int node = blockIdx.x * 4 + (threadIdx.x >> 6);
    if (node >= NN) return;
    int lane = threadIdx.x & 63;
    float scx = 0.f, scy = 0.f, shx = 0.f, shy = 0.f;
    if (BN) {
        int c0 = lane * 2, c1 = lane * 2 + 1;
        float mu0 = stats[c0] * (1.f / NN);
        float mu1 = stats[c1] * (1.f / NN);
        float var0 = stats[DIM + c0] * (1.f / NN) - mu0 * mu0;
        float var1 = stats[DIM + c1] * (1.f / NN) - mu1 * mu1;
        scx = gamma[c0] * rsqrtf(var0 + BN_EPS);
        scy = gamma[c1] * rsqrtf(var1 + BN_EPS);
        shx = beta[c0] - mu0 * scx;
        shy = beta[c1] - mu1 * scy;
    }
    int beg = offsets[node], end = offsets[node + 1];
    float ax, ay;
    if (BN) {
        unsigned p = ((const unsigned*)((const unsigned short*)Zin + (size_t)node * DIM))[lane];
        ax = lrelu(bf2f((unsigned short)p) * scx + shx);
        ay = lrelu(bf2f((unsigned short)(p >> 16)) * scy + shy);
    } else {
        float2 v = *(const float2*)((const float*)Zin + (size_t)node * DIM + lane * 2);
        ax = v.x; ay = v.y;
    }

    for (int base = beg; base < end; base += 64) {
        int cnt = min(64, end - base);
        int myidx = (lane < cnt) ? csr_src[base + lane] : 0;
        int e = 0;
        for (; e + 4 <= cnt; e += 4) {
            int i0 = __shfl(myidx, e);
            int i1 = __shfl(myidx, e + 1);
            int i2 = __shfl(myidx, e + 2);
            int i3 = __shfl(myidx, e + 3);
            if (BN) {
                const unsigned short* zb = (const unsigned short*)Zin;
                unsigned p0 = ((const unsigned*)(zb + (size_t)i0 * DIM))[lane];
                unsigned p1 = ((const unsigned*)(zb + (size_t)i1 * DIM))[lane];
                unsigned p2 = ((const unsigned*)(zb + (size_t)i2 * DIM))[lane];
                unsigned p3 = ((const unsigned*)(zb + (size_t)i3 * DIM))[lane];
                ax += lrelu(bf2f((unsigned short)p0) * scx + shx) +
                      lrelu(bf2f((unsigned short)p1) * scx + shx) +
                      lrelu(bf2f((unsigned short)p2) * scx + shx) +
                      lrelu(bf2f((unsigned short)p3) * scx + shx);
                ay += lrelu(bf2f((unsigned short)(p0 >> 16)) * scy + shy) +
                      lrelu(bf2f((unsigned short)(p1 >> 16)) * scy + shy) +
                      lrelu(bf2f((unsigned short)(p2 >> 16)) * scy + shy) +
                      lrelu(bf2f((unsigned short)(p3 >> 16)) * scy + shy);
            } else {
                const float* zf = (const float*)Zin;
                float2 w0 = *(const float2*)(zf + (size_t)i0 * DIM + lane * 2);
                float2 w1 = *(const float2*)(zf + (size_t)i1 * DIM + lane * 2);
                float2 w2 = *(const float2*)(zf + (size_t)i2 * DIM + lane * 2);
                float2 w3 = *(const float2*)(zf + (size_t)i3 * DIM + lane * 2);
                ax += (w0.x + w1.x) + (w2.x + w3.x);
                ay += (w0.y + w1.y) + (w2.y + w3.y);
            }
        }
        for (; e < cnt; e++) {
            int i0 = __shfl(myidx, e);
            if (BN) {
                unsigned p = ((const unsigned*)((const unsigned short*)Zin + (size_t)i0 * DIM))[lane];
                ax += lrelu(bf2f((unsigned short)p) * scx + shx);
                ay += lrelu(bf2f((unsigned short)(p >> 16)) * scy + shy);
            } else {
                float2 w = *(const float2*)((const float*)Zin + (size_t)i0 * DIM + lane * 2);
                ax += w.x; ay += w.y;
            }
        }
    }
    float2 o; o.x = ax; o.y = ay;
    *(float2*)(hz + (size_t)node * DIM + (size_t)lane * 2) = o;
}

// ---------------- fused MLP v4c: 4 weight mats in LDS, 256 rows/block, 4 slabs,
// in-register BN stats, z written as bf16, cvt-based hi/lo split.
__device__ __forceinline__ int t1idx(int row, int col) {
    return (row * 128 + col) ^ ((row & 7) << 2);
}

__global__ __launch_bounds__(256) void mlp_mfma(const float* __restrict__ hz,
                                                const unsigned short* __restrict__ W1h,
                                                const unsigned short* __restrict__ W1l,
                                                const float* __restrict__ b1,
                                                const unsigned short* __restrict__ W2h,
                                                const unsigned short* __restrict__ W2l,
                                                const float* __restrict__ b2,
                                                unsigned short* __restrict__ Zb,
                                                float* __restrict__ stats) {
    __shared__ unsigned short wlds[4][16384];  // 128 KB
    __shared__ float t1s[8192];                // 32 KB swizzled
    int tid = threadIdx.x;
    int w = tid >> 6, l = tid & 63;
    int l15 = l & 15, kg = l >> 4;

    float bias1[8], bias2[8];
#pragma unroll
    for (int nt = 0; nt < 8; nt++) {
        bias1[nt] = b1[nt * 16 + l15];
        bias2[nt] = b2[nt * 16 + l15];
    }
    {
        const float4* s0 = (const float4*)W1h;
        const float4* s1 = (const float4*)W1l;
        const float4* s2 = (const float4*)W2h;
        const float4* s3 = (const float4*)W2l;
        float4* d0 = (float4*)wlds[0];
        float4* d1 = (float4*)wlds[1];
        float4* d2 = (float4*)wlds[2];
        float4* d3 = (float4*)wlds[3];
        for (int i = tid; i < 2048; i += 256) {
            d0[i] = s0[i]; d1[i] = s1[i]; d2[i] = s2[i]; d3[i] = s3[i];
        }
    }
    __syncthreads();

    float sacc[8], s2acc[8];
#pragma unroll
    for (int nt = 0; nt < 8; nt++) { sacc[nt] = 0.f; s2acc[nt] = 0.f; }

    int blk0 = blockIdx.x * 256;
    float4 abuf[8];
    {
        int mrow = blk0 + w * 16 + l15;
#pragma unroll
        for (int kb = 0; kb < 4; kb++) {
            if (mrow < NN) {
                abuf[kb * 2]     = *(const float4*)(hz + (size_t)mrow * DIM + kb * 32 + kg * 8);
                abuf[kb * 2 + 1] = *(const float4*)(hz + (size_t)mrow * DIM + kb * 32 + kg * 8 + 4);
            } else {
                abuf[kb * 2] = make_float4(0.f, 0.f, 0.f, 0.f);
                abuf[kb * 2 + 1] = make_float4(0.f, 0.f, 0.f, 0.f);
            }
        }
    }

#pragma unroll
    for (int slab = 0; slab < 4; slab++) {
        bf16x8 ah[4], al[4];
#pragma unroll
        for (int kb = 0; kb < 4; kb++) split8v(abuf[kb * 2], abuf[kb * 2 + 1], ah[kb], al[kb]);
        if (slab < 3) {
            int mrow = blk0 + (slab + 1) * 64 + w * 16 + l15;
#pragma unroll
            for (int kb = 0; kb < 4; kb++) {
                if (mrow < NN) {
                    abuf[kb * 2]     = *(const float4*)(hz + (size_t)mrow * DIM + kb * 32 + kg * 8);
                    abuf[kb * 2 + 1] = *(const float4*)(hz + (size_t)mrow * DIM + kb * 32 + kg * 8 + 4);
                } else {
                    abuf[kb * 2] = make_float4(0.f, 0.f, 0.f, 0.f);
                    abuf[kb * 2 + 1] = make_float4(0.f, 0.f, 0.f, 0.f);
                }
            }
        }
#pragma unroll
        for (int nt = 0; nt < 8; nt++) {
            f32x4 a0 = {0.f, 0.f, 0.f, 0.f}, a1 = a0, a2 = a0;
#pragma unroll
            for (int kb = 0; kb < 4; kb++) {
                int off = nt * 2048 + kb * 512 + l * 8;
                bf16x8 wh = *(const bf16x8*)(&wlds[0][off]);
                bf16x8 wl = *(const bf16x8*)(&wlds[1][off]);
                a0 = __builtin_amdgcn_mfma_f32_16x16x32_bf16(ah[kb], wh, a0, 0, 0, 0);
                a1 = __builtin_amdgcn_mfma_f32_16x16x32_bf16(ah[kb], wl, a1, 0, 0, 0);
                a2 = __builtin_amdgcn_mfma_f32_16x16x32_bf16(al[kb], wh, a2, 0, 0, 0);
            }
            int colw = nt * 16 + l15;
#pragma unroll
            for (int j = 0; j < 4; j++) {
                t1s[t1idx(w * 16 + kg * 4 + j, colw)] = lrelu(a0[j] + a1[j] + a2[j] + bias1[nt]);
            }
        }
        bf16x8 a2h[4], a2l[4];
#pragma unroll
        for (int kb = 0; kb < 4; kb++) {
            int c = kb * 32 + kg * 8;
            float4 q0 = *(const float4*)(&t1s[t1idx(w * 16 + l15, c)]);
            float4 q1 = *(const float4*)(&t1s[t1idx(w * 16 + l15, c + 4)]);
            split8v(q0, q1, a2h[kb], a2l[kb]);
        }
#pragma unroll
        for (int nt = 0; nt < 8; nt++) {
            f32x4 a0 = {0.f, 0.f, 0.f, 0.f}, a1 = a0, a2 = a0;
#pragma unroll
            for (int kb = 0; kb < 4; kb++) {
                int off = nt * 2048 + kb * 512 + l * 8;
                bf16x8 wh = *(const bf16x8*)(&wlds[2][off]);
                bf16x8 wl = *(const bf16x8*)(&wlds[3][off]);
                a0 = __builtin_amdgcn_mfma_f32_16x16x32_bf16(a2h[kb], wh, a0, 0, 0, 0);
                a1 = __builtin_amdgcn_mfma_f32_16x16x32_bf16(a2h[kb], wl, a1, 0, 0, 0);
                a2 = __builtin_amdgcn_mfma_f32_16x16x32_bf16(a2l[kb], wh, a2, 0, 0, 0);
            }
#pragma unroll
            for (int j = 0; j < 4; j++) {
                int r = blk0 + slab * 64 + w * 16 + kg * 4 + j;
                if (r < NN) {
                    float o = a0[j] + a1[j] + a2[j] + bias2[nt];
                    Zb[(size_t)r * DIM + nt * 16 + l15] = f2bf(o);
                    sacc[nt] += o;
                    s2acc[nt] += o * o;
                }
            }
        }
    }

    __syncthreads();
    int part = w * 4 + kg;
#pragma unroll
    for (int nt = 0; nt < 8; nt++) {
        t1s[part * 128 + nt * 16 + l15] = sacc[nt];
        t1s[2048 + part * 128 + nt * 16 + l15] = s2acc[nt];
    }
    __syncthreads();
    if (tid < DIM) {
        float ts = 0.f, ts2 = 0.f;
#pragma unroll
        for (int p = 0; p < 16; p++) {
            ts += t1s[p * 128 + tid];
            ts2 += t1s[2048 + p * 128 + tid];
        }
        atomicAdd(&stats[tid], ts);
        atomicAdd(&stats[DIM + tid], ts2);
    }
}

// ---------------- fused gumbel softmax + pool
__global__ __launch_bounds__(256) void softpool_kernel(const unsigned short* __restrict__ Zb,
                                                       const float* __restrict__ stats,
                                                       const float* __restrict__ gamma,
                                                       const float* __restrict__ beta,
                                                       const float* __restrict__ G,
                                                       const int* __restrict__ batch,
                                                       float* __restrict__ C,
                                                       float* __restrict__ pooled) {
    int wv = threadIdx.x >> 6;
    int lane = threadIdx.x & 63;
    int n0 = blockIdx.x * 64 + wv * 16;
    if (n0 >= NN) return;
    int n1 = min(NN, n0 + 16);
    int c0 = lane * 2, c1 = lane * 2 + 1;
    float mu0 = stats[c0] * (1.f / NN);
    float mu1 = stats[c1] * (1.f / NN);
    float var0 = stats[DIM + c0] * (1.f / NN) - mu0 * mu0;
    float var1 = stats[DIM + c1] * (1.f / NN) - mu1 * mu1;
    float scx = gamma[c0] * rsqrtf(var0 + BN_EPS);
    float scy = gamma[c1] * rsqrtf(var1 + BN_EPS);
    float shx = beta[c0] - mu0 * scx;
    float shy = beta[c1] - mu1 * scy;

    int curg = batch[n0];
    float px = 0.f, py = 0.f;
    for (int node = n0; node < n1; node++) {
        int g = batch[node];
        if (g != curg) {
            atomicAdd(&pooled[curg * DIM + c0], px);
            atomicAdd(&pooled[curg * DIM + c1], py);
            px = 0.f; py = 0.f;
            curg = g;
        }
        unsigned p = ((const unsigned*)(Zb + (size_t)node * DIM))[lane];
        float2 gv = *(const float2*)(G + (size_t)node * DIM + lane * 2);
        float vx = bf2f((unsigned short)p) * scx + shx + gv.x;
        float vy = bf2f((unsigned short)(p >> 16)) * scy + shy + gv.y;
        float m = fmaxf(vx, vy);
#pragma unroll
        for (int o = 32; o >= 1; o >>= 1) m = fmaxf(m, __shfl_xor(m, o));
        float ex = __expf(vx - m), ey = __expf(vy - m);
        float s = ex + ey;
#pragma unroll
        for (int o = 32; o >= 1; o >>= 1) s += __shfl_xor(s, o);
        float inv = 1.f / s;
        float cx = ex * inv, cy = ey * inv;
        float2 c; c.x = cx; c.y = cy;
        *(float2*)(C + (size_t)node * DIM + lane * 2) = c;
        px += cx; py += cy;
    }
    atomicAdd(&pooled[curg * DIM + c0], px);
    atomicAdd(&pooled[curg * DIM + c1], py);
}

// ---------------- dense head
__global__ __launch_bounds__(128) void head_kernel(const float* __restrict__ pooled,
                                                   const float* __restrict__ Wd1,
                                                   const float* __restrict__ bd1,
                                                   const float* __restrict__ Wd2,
                                                   const float* __restrict__ bd2,
                                                   float* __restrict__ out) {
    int g = blockIdx.x;
    int j = threadIdx.x;
    __shared__ float hid[DIM];
    __shared__ float logits[NCLASSES];
    float acc = bd1[j];
    for (int k = 0; k < DIM; k++) acc += pooled[g * DIM + k] * Wd1[k * DIM + j];
    hid[j] = lrelu(acc);
    __syncthreads();
    if (j < NCLASSES) {
        float a = bd2[j];
        for (int k = 0; k < DIM; k++) a += hid[k] * Wd2[k * NCLASSES + j];
        logits[j] = a;
    }
    __syncthreads();
    if (j == 0) {
        float m = -1e30f;
        for (int c = 0; c < NCLASSES; c++) m = fmaxf(m, logits[c]);
        float s = 0.f, e[NCLASSES];
        for (int c = 0; c < NCLASSES; c++) { e[c] = __expf(logits[c] - m); s += e[c]; }
        float inv = 1.f / s;
        for (int c = 0; c < NCLASSES; c++) out[g * NCLASSES + c] = e[c] * inv;
    }
}

extern "C" void kernel_launch(void* const* d_in, const int* in_sizes, int n_in,
                              void* d_out, int out_size, void* d_ws, size_t ws_size,
                              hipStream_t stream) {
    const float* x = (const float*)d_in[0];
    const int* edges = (const int*)d_in[1];
    const int* batch = (const int*)d_in[2];
    const float* gum = (const float*)d_in[3];
    const float* W1s = (const float*)d_in[4];
    const float* b1s = (const float*)d_in[5];
    const float* W2s = (const float*)d_in[6];
    const float* b2s = (const float*)d_in[7];
    const float* gammas = (const float*)d_in[8];
    const float* betas = (const float*)d_in[9];
    const float* Wd1 = (const float*)d_in[10];
    const float* bd1 = (const float*)d_in[11];
    const float* Wd2 = (const float*)d_in[12];
    const float* bd2 = (const float*)d_in[13];

    float* out = (float*)d_out;
    float* cout = out + NGRAPHS * NCLASSES;

    const size_t ND = (size_t)NN * DIM;
    unsigned short* zb = (unsigned short*)d_ws;      // ND bf16 (pre-BN layer output)
    float* hz = (float*)(zb + ND);                   // ND f32 (gather out / MLP in)
    unsigned short* Wh = (unsigned short*)(hz + ND); // 16*16384 bf16 (frag-major hi)
    unsigned short* Wl = Wh + 16 * 16384;            // 16*16384 bf16 (frag-major lo)
    float* stats8 = (float*)(Wl + 16 * 16384);       // 8 * 2*DIM
    float* pooled = stats8 + NLAYERS * 2 * DIM;      // NGRAPHS*DIM
    int* counts = (int*)(pooled + NGRAPHS * DIM);    // NN
    int* offsets = counts + NN;                      // NN+1
    int* cursor = offsets + NN + 1;                  // NN
    int* csr_src = cursor + NN;                      // NE
    int* psums = csr_src + NE;                       // SCAN_BLOCKS

    const int MLP_BLOCKS = (NN + 255) / 256;
    const int EDGE_BLOCKS = (NE + 255) / 256;
    const int NODE_BLOCKS = (NN + 3) / 4;
    const int SP_BLOCKS = (NN + 63) / 64;

    // ---- CSR build + weight prep (static per launch)
    hipMemsetAsync(counts, 0, NN * sizeof(int), stream);
    degree_kernel<<<EDGE_BLOCKS, 256, 0, stream>>>(edges, counts);
    psum_kernel<<<SCAN_BLOCKS, 256, 0, stream>>>(counts, psums);
    pscan_kernel<<<1, 256, 0, stream>>>(psums);
    owrite_kernel<<<SCAN_BLOCKS, 256, 0, stream>>>(counts, psums, offsets, cursor);
    fill_kernel<<<EDGE_BLOCKS, 256, 0, stream>>>(edges, cursor, csr_src);
    wprep_kernel<<<(16 * 16384 + 255) / 256, 256, 0, stream>>>(W1s, W2s, Wh, Wl);

    hipMemsetAsync(stats8, 0, NLAYERS * 2 * DIM * sizeof(float), stream);

    for (int i = 0; i < NLAYERS; i++) {
        const unsigned short* W1h = Wh + (size_t)(2 * i) * 16384;
        const unsigned short* W1l = Wl + (size_t)(2 * i) * 16384;
        const unsigned short* W2h = Wh + (size_t)(2 * i + 1) * 16384;
        const unsigned short* W2l = Wl + (size_t)(2 * i + 1) * 16384;
        const float* b1 = b1s + (size_t)i * DIM;
        const float* b2 = b2s + (size_t)i * DIM;
        float* stats = stats8 + (size_t)i * 2 * DIM;

        if (i == 0)
            gather_kernel<0><<<NODE_BLOCKS, 256, 0, stream>>>(x, nullptr, nullptr, nullptr,
                                                              offsets, csr_src, hz);
        else
            gather_kernel<1><<<NODE_BLOCKS, 256, 0, stream>>>(
                zb, stats8 + (size_t)(i - 1) * 2 * DIM, gammas + (size_t)(i - 1) * DIM,
                betas + (size_t)(i - 1) * DIM, offsets, csr_src, hz);
        mlp_mfma<<<MLP_BLOCKS, 256, 0, stream>>>(hz, W1h, W1l, b1, W2h, W2l, b2, zb, stats);
    }

    hipMemsetAsync(pooled, 0, NGRAPHS * DIM * sizeof(float), stream);
    softpool_kernel<<<SP_BLOCKS, 256, 0, stream>>>(
        zb, stats8 + (size_t)(NLAYERS - 1) * 2 * DIM, gammas + (size_t)(NLAYERS - 1) * DIM,
        betas + (size_t)(NLAYERS - 1) * DIM, gum, batch, cout, pooled);
    head_kernel<<<NGRAPHS, 128, 0, stream>>>(pooled, Wd1, bd1, Wd2, bd2, out);
}